// Round 6
// baseline (1102.644 us; speedup 1.0000x reference)
//
#include <hip/hip_runtime.h>
#include <hip/hip_bf16.h>
#include <stdint.h>

typedef __bf16 bf16;
typedef __bf16 bf16x8 __attribute__((ext_vector_type(8)));
typedef float f32x4 __attribute__((ext_vector_type(4)));
typedef unsigned short u16t;
typedef unsigned int u32t;

#define MFMA16(a, b, c) __builtin_amdgcn_mfma_f32_16x16x32_bf16((a), (b), (c), 0, 0, 0)

typedef const void __attribute__((address_space(1))) cg_void;
typedef void __attribute__((address_space(3))) lds_void;
#define GLL16(g, l) __builtin_amdgcn_global_load_lds((cg_void*)(g), (lds_void*)(l), 16, 0, 0)
#define VWAIT(n) asm volatile("s_waitcnt vmcnt(" #n ")" ::: "memory")

// ---------------- ws layout (bytes) ----------------
#define OFF_FLAG   0
#define OFF_BQKV   256
#define OFF_BPROJ  6400
#define OFF_WQKVT  8448
#define OFF_WPROJT 1581312
#define OFF_QKV    2105600      // attn-out lives here (134 MB; qkv never materialized)
#define OFF_ATTN   404758784
#define OFF_XB     404758784    // xb (bf16 x)

// head-triple permutation: reordered-W^T row n <- original qkv col src(n)
// h = n/96, r = n%96, part = r/32 (0=Q,1=K,2=V), d = r%32; src = part*512 + h*32 + d

// ---------------- dtype detector ----------------
__global__ __launch_bounds__(256) void k_detect(const u16t* x, u32t* flag) {
    __shared__ int cnt;
    if (threadIdx.x == 0) cnt = 0;
    __syncthreads();
    u16t h = x[threadIdx.x * 2];
    int e = (h >> 7) & 0xFF;
    int ok = (h == 0) || (e >= 100 && e <= 134);
    atomicAdd(&cnt, ok);
    __syncthreads();
    if (threadIdx.x == 0) flag[0] = (cnt >= 200) ? 1u : 0u;
}

// ---------------- x f32 -> bf16 pre-pass (skipped when input already bf16) ----
__global__ __launch_bounds__(256) void k_cvt(const float* x, bf16* xb, const u32t* flagp) {
    if (flagp[0]) return;
    const size_t TOT = (size_t)131072 * 512;
    size_t i = (size_t)(blockIdx.x * 256 + threadIdx.x) * 8;
    const size_t stride = (size_t)gridDim.x * 256 * 8;
    for (; i < TOT; i += stride) {
        float4 v0 = *(const float4*)(x + i);
        float4 v1 = *(const float4*)(x + i + 4);
        bf16x8 h;
        h[0] = (bf16)v0.x; h[1] = (bf16)v0.y; h[2] = (bf16)v0.z; h[3] = (bf16)v0.w;
        h[4] = (bf16)v1.x; h[5] = (bf16)v1.y; h[6] = (bf16)v1.z; h[7] = (bf16)v1.w;
        *(bf16x8*)(xb + i) = h;
    }
}

// ---------------- weight transpose: W[512][N] -> Wt[N][512] bf16 ----------------
template <int N, bool PERM>
__global__ __launch_bounds__(256) void k_trans(const void* W, bf16* Wt, const u32t* flagp) {
    __shared__ float T[64][65];
    const int isbf = (int)flagp[0];
    const int n0 = blockIdx.x * 64, k0 = blockIdx.y * 64;
    const int t = threadIdx.x;
    const int lc = t & 63, lr = t >> 6;
#pragma unroll
    for (int rr = 0; rr < 16; ++rr) {
        int row = rr * 4 + lr;
        int col = n0 + lc;
        int srcc = col;
        if (PERM) {
            int h = col / 96, r = col % 96;
            srcc = (r >> 5) * 512 + h * 32 + (r & 31);
        }
        size_t g = (size_t)(k0 + row) * N + srcc;
        float v = isbf ? (float)((const bf16*)W)[g] : ((const float*)W)[g];
        T[row][lc] = v;
    }
    __syncthreads();
#pragma unroll
    for (int rr = 0; rr < 16; ++rr) {
        int row = rr * 4 + lr;
        Wt[(size_t)(n0 + row) * 512 + k0 + lc] = (bf16)T[lc][row];
    }
}

// ---------------- bias prep -> f32 (bq permuted to head-triple order) ----------
__global__ __launch_bounds__(256) void k_bias(const void* b_qkv, const void* b_proj,
                                              const u32t* flagp, char* ws) {
    float* bq = (float*)(ws + OFF_BQKV);
    float* bp = (float*)(ws + OFF_BPROJ);
    const int isbf = (int)flagp[0];
    int gid = blockIdx.x * 256 + threadIdx.x;
    if (gid < 1536) {
        int h = gid / 96, r = gid % 96;
        int src = (r >> 5) * 512 + h * 32 + (r & 31);
        bq[gid] = isbf ? (float)((const bf16*)b_qkv)[src] : ((const float*)b_qkv)[src];
    } else if (gid < 2048) {
        int o = gid - 1536;
        bp[o] = isbf ? (float)((const bf16*)b_proj)[o] : ((const float*)b_proj)[o];
    }
}

// ---------------- proj GEMM (round-3 256^2 8-phase template, unchanged) -------
template <int NTOT>
__global__ __launch_bounds__(512, 2) void k_gemm(const void* Ax, const bf16* Axb, const bf16* Bt,
                                                 const float* bias, void* Cp,
                                                 const u32t* flagp, int omode) {
    __shared__ __align__(16) u16t As[2 * 16384];
    __shared__ __align__(16) u16t Bs[2 * 16384];
    constexpr int NBN = NTOT / 256;
    const int isbf = (int)flagp[0];
    const int out_bf16 = (omode == 1) || isbf;
    const bf16* Ab = isbf ? (const bf16*)Ax : Axb;

    const int t = threadIdx.x;
    const int w = t >> 6, lane = t & 63;
    const int ln = lane & 15, qd = lane >> 4;
    const int wm = w >> 2, wn = w & 3;

    const int flat = blockIdx.x;
    const int xcd = flat & 7, slot = flat >> 3;
    const int n_idx = slot % NBN, grp = slot / NBN;
    const int m0 = (grp * 8 + xcd) * 256;
    const int n0 = n_idx * 256;

    const int l8 = lane >> 3, pc = lane & 7;
    const int cs8 = (pc ^ l8) * 8;
    u32t aoff[2][2], boff[2][2];
    int adst[2][2], bdst[2][2];
#pragma unroll
    for (int s = 0; s < 2; ++s)
#pragma unroll
        for (int q2 = 0; q2 < 2; ++q2) {
            int rA = q2 * 128 + s * 64 + w * 8;
            aoff[s][q2] = (u32t)(m0 + rA + l8) * 512 + cs8;
            adst[s][q2] = rA * 64;
            int rB = (q2 * 2 + (w >> 2)) * 64 + s * 32 + (w & 3) * 8;
            boff[s][q2] = (u32t)(n0 + rB + l8) * 512 + cs8;
            bdst[s][q2] = rB * 64;
        }

    const int p0 = (qd ^ (ln & 7)) * 8;
    int abase[4], bbase[2];
#pragma unroll
    for (int i = 0; i < 4; ++i) abase[i] = (wm * 128 + i * 16 + ln) * 64 + p0;
#pragma unroll
    for (int j = 0; j < 2; ++j) bbase[j] = (wn * 64 + j * 16 + ln) * 64 + p0;

    f32x4 acc[8][4];
    f32x4 zero = {0.f, 0.f, 0.f, 0.f};
#pragma unroll
    for (int i = 0; i < 8; ++i)
#pragma unroll
        for (int j = 0; j < 4; ++j) acc[i][j] = zero;

    auto stageA = [&](int s, int buf, int kt) {
#pragma unroll
        for (int q2 = 0; q2 < 2; ++q2)
            GLL16(Ab + aoff[s][q2] + kt * 64, &As[buf * 16384 + adst[s][q2]]);
    };
    auto stageB = [&](int s, int buf, int kt) {
#pragma unroll
        for (int q2 = 0; q2 < 2; ++q2)
            GLL16(Bt + boff[s][q2] + kt * 64, &Bs[buf * 16384 + bdst[s][q2]]);
    };

#define PH(BUF, QM, QN, STG, WAITOP)                                             \
    {                                                                            \
        bf16x8 af[4][2], bv[2][2];                                               \
        const u16t* Ap = &As[(BUF) * 16384 + (QM) * 4096];                       \
        const u16t* Bp = &Bs[(BUF) * 16384 + (QN) * 2048];                       \
        _Pragma("unroll") for (int i = 0; i < 4; ++i) {                          \
            af[i][0] = *(const bf16x8*)(const void*)&Ap[abase[i]];               \
            af[i][1] = *(const bf16x8*)(const void*)&Ap[abase[i] ^ 32];          \
        }                                                                        \
        _Pragma("unroll") for (int j = 0; j < 2; ++j) {                          \
            bv[j][0] = *(const bf16x8*)(const void*)&Bp[bbase[j]];               \
            bv[j][1] = *(const bf16x8*)(const void*)&Bp[bbase[j] ^ 32];          \
        }                                                                        \
        STG;                                                                     \
        WAITOP;                                                                  \
        __builtin_amdgcn_s_barrier();                                            \
        __builtin_amdgcn_s_setprio(1);                                           \
        _Pragma("unroll") for (int i = 0; i < 4; ++i)                            \
            _Pragma("unroll") for (int j = 0; j < 2; ++j) {                      \
                acc[(QM) * 4 + i][(QN) * 2 + j] =                                \
                    MFMA16(af[i][0], bv[j][0], acc[(QM) * 4 + i][(QN) * 2 + j]); \
                acc[(QM) * 4 + i][(QN) * 2 + j] =                                \
                    MFMA16(af[i][1], bv[j][1], acc[(QM) * 4 + i][(QN) * 2 + j]); \
            }                                                                    \
        __builtin_amdgcn_s_setprio(0);                                           \
        __builtin_amdgcn_s_barrier();                                            \
    }

    stageA(0, 0, 0);
    stageB(0, 0, 0);
    stageB(1, 0, 0);
    stageA(1, 0, 0);
    VWAIT(4);
    __builtin_amdgcn_s_barrier();

    for (int kt = 0; kt < 7; ++kt) {
        const int buf = kt & 1, nb = buf ^ 1, k1 = kt + 1;
        PH(buf, 0, 0, stageA(0, nb, k1), VWAIT(4));
        PH(buf, 0, 1, stageB(0, nb, k1), VWAIT(4));
        PH(buf, 1, 0, stageB(1, nb, k1), VWAIT(6));
        PH(buf, 1, 1, stageA(1, nb, k1), VWAIT(4));
    }
    PH(1, 0, 0, (void)0, VWAIT(2));
    PH(1, 0, 1, (void)0, VWAIT(0));
    PH(1, 1, 0, (void)0, (void)0);
    PH(1, 1, 1, (void)0, (void)0);
#undef PH

    float bj[4];
#pragma unroll
    for (int j = 0; j < 4; ++j) bj[j] = bias[n0 + wn * 64 + j * 16 + ln];

    if (out_bf16) {
        bf16* C = (bf16*)Cp;
#pragma unroll
        for (int i = 0; i < 8; ++i)
#pragma unroll
            for (int j = 0; j < 4; ++j)
#pragma unroll
                for (int rr = 0; rr < 4; ++rr) {
                    size_t row = (size_t)m0 + wm * 128 + i * 16 + qd * 4 + rr;
                    int col = n0 + wn * 64 + j * 16 + ln;
                    C[row * NTOT + col] = (bf16)(acc[i][j][rr] + bj[j]);
                }
    } else {
        float* C = (float*)Cp;
#pragma unroll
        for (int i = 0; i < 8; ++i)
#pragma unroll
            for (int j = 0; j < 4; ++j)
#pragma unroll
                for (int rr = 0; rr < 4; ++rr) {
                    size_t row = (size_t)m0 + wm * 128 + i * 16 + qd * 4 + rr;
                    int col = n0 + wn * 64 + j * 16 + ln;
                    C[row * NTOT + col] = acc[i][j][rr] + bj[j];
                }
    }
}

// ---------------- MEGA: barrier-free QKV GEMM + attention, wave = (window,head) ----
// Block = 1 window (64 tokens) x 8 heads (768 permuted cols); 4096 blocks x 512 thr.
// A (x rows, 64x512 bf16) staged to LDS in two 32-KB K-halves (chunk-XOR swizzle,
// GLL16). B (wqkvT, L2-resident) loaded DIRECTLY global->VGPR per K-tile: per
// (j,kk) one dwordx4; wave pattern = 16 rows x 64 B contiguous -> fully coalesced,
// one 128-B line per row per K-tile consumed exactly. K-loop has NO barriers; only
// 4 barriers/block total (A-half swap). Wave w owns head g = hb*8+w completely:
// acc[4][6] = full Q|K|V triple (j0,1=Q j2,3=K j4,5=V). Stash to wave-PRIVATE
// patch (no block sync), then verbatim attention math, write attn-out only.
// Accumulation order per acc element identical to prior rounds (kt 0..7, kk 0,1).
__global__ __launch_bounds__(512, 2) void k_mega(const void* Ax, const bf16* Axb,
                                                 const bf16* Bt, const float* bias,
                                                 bf16* attnout, const u32t* flagp) {
    __shared__ __align__(16) u16t Axs[16384];       // 32 KB: A K-half [64][256] swz
    __shared__ __align__(16) u16t patch[8][6656];   // 106.5 KB: per-wave QK|P / V
    const int isbf = (int)flagp[0];
    const bf16* Ab = isbf ? (const bf16*)Ax : Axb;

    const int t = threadIdx.x;
    const int w = t >> 6, lane = t & 63;
    const int ln = lane & 15, qd = lane >> 4, q8 = qd * 8;

    // XCD-chunked: consecutive slots on one XCD share the window (A L2 reuse)
    const int flat = blockIdx.x;
    const int xcd = flat & 7, slot = flat >> 3;
    const int hb = slot & 1;
    const int win = xcd * 256 + (slot >> 1);
    const int g = hb * 8 + w;                      // head index (original order)
    const size_t xbase = (size_t)win * 64 * 512;

    // A staging: 4 GLL16/wave; GLL16 q stages rows w*8+2q, w*8+2q+1 (1024 B).
    // LDS[row][phys chunk p] = x[row][p ^ (row&7)]  (16-B chunks)
    u32t asrc[4];
#pragma unroll
    for (int q = 0; q < 4; ++q) {
        int row = w * 8 + q * 2 + (lane >> 5);
        asrc[q] = (u32t)row * 512 + (u32t)(((lane & 31) ^ (row & 7)) * 8);
    }

    // B base pointers: col n = g*96 + j*16 + ln (permuted wqkvT rows), k-octet qd
    const bf16* bp6[6];
#pragma unroll
    for (int j = 0; j < 6; ++j)
        bp6[j] = Bt + (size_t)(g * 96 + j * 16 + ln) * 512 + q8;

    f32x4 acc[4][6];
    f32x4 zero = {0.f, 0.f, 0.f, 0.f};
#pragma unroll
    for (int i = 0; i < 4; ++i)
#pragma unroll
        for (int j = 0; j < 6; ++j) acc[i][j] = zero;

#pragma unroll
    for (int kh = 0; kh < 2; ++kh) {
        if (kh) __builtin_amdgcn_s_barrier();      // all waves done with half 0
#pragma unroll
        for (int q = 0; q < 4; ++q)
            GLL16(Ab + xbase + kh * 256 + asrc[q], &Axs[(w * 8 + q * 2) * 256]);
        VWAIT(0);
        __builtin_amdgcn_s_barrier();
#pragma unroll
        for (int kt = 0; kt < 4; ++kt) {
            const int kg = kh * 4 + kt;            // global K-tile 0..7
            bf16x8 bfr[6][2];
#pragma unroll
            for (int j = 0; j < 6; ++j) {
                bfr[j][0] = *(const bf16x8*)(bp6[j] + kg * 64);
                bfr[j][1] = *(const bf16x8*)(bp6[j] + kg * 64 + 32);
            }
#pragma unroll
            for (int kk = 0; kk < 2; ++kk) {
                bf16x8 af[4];
#pragma unroll
                for (int i = 0; i < 4; ++i) {
                    int row = i * 16 + ln;
                    int chunk = kt * 8 + kk * 4 + qd;
                    af[i] = *(const bf16x8*)(const void*)
                        &Axs[row * 256 + (chunk ^ (row & 7)) * 8];
                }
                __builtin_amdgcn_s_setprio(1);
#pragma unroll
                for (int i = 0; i < 4; ++i)
#pragma unroll
                    for (int j = 0; j < 6; ++j)
                        acc[i][j] = MFMA16(af[i], bfr[j][kk], acc[i][j]);
                __builtin_amdgcn_s_setprio(0);
            }
        }
    }

    // ---- stash Q,K,V (+bias) into the wave's PRIVATE patch (no block sync) ----
    float bj[6];
#pragma unroll
    for (int j = 0; j < 6; ++j) bj[j] = bias[g * 96 + j * 16 + ln];
    u16t* pw = patch[w];
#pragma unroll
    for (int i = 0; i < 4; ++i)
#pragma unroll
        for (int j = 0; j < 6; ++j) {
            int part = j >> 1;                     // 0=Q 1=K 2=V
            int d = (j & 1) * 16 + ln;
#pragma unroll
            for (int rr = 0; rr < 4; ++rr) {
                int tok = i * 16 + qd * 4 + rr;
                bf16 val = (bf16)(acc[i][j][rr] + bj[j]);
                int idx;
                if (part == 2)
                    idx = 4608 + tok * 32 +
                          (((d >> 3) ^ (((tok >> 3) ^ tok) & 3)) << 3) + (d & 7);
                else
                    idx = part * 2048 + tok * 32 +
                          (((d >> 3) ^ ((tok >> 1) & 3)) << 3) + (d & 7);
                *(bf16*)&pw[idx] = val;
            }
        }

    // ---- attention for (win, head g): verbatim math ----
    {
        const int hcol = g * 32;
        const int qswz = (qd ^ ((ln >> 1) & 3)) * 8;

        bf16x8 aq[4], bk[4];
#pragma unroll
        for (int i = 0; i < 4; ++i)
            aq[i] = *(const bf16x8*)(const void*)&pw[(i * 16 + ln) * 32 + qswz];
#pragma unroll
        for (int j = 0; j < 4; ++j)
            bk[j] = *(const bf16x8*)(const void*)&pw[2048 + (j * 16 + ln) * 32 + qswz];

        f32x4 zro = {0.f, 0.f, 0.f, 0.f};
        f32x4 s[4][4];
#pragma unroll
        for (int i = 0; i < 4; ++i)
#pragma unroll
            for (int j = 0; j < 4; ++j) s[i][j] = MFMA16(aq[i], bk[j], zro);

        const float INV2S2 = 3.28731097961867f;  // 1/(2*0.39^2)
        {
            int c = lane & 7;
            float S1 = 0.f;
#pragma unroll
            for (int c2 = 0; c2 < 8; ++c2) {
                int dd = c - c2;
                S1 += __expf(-(float)(dd * dd) * INV2S2);
            }
            float invS1 = 1.0f / S1;
            const int ymb = ln >> 3, xm = ln & 7, yq = qd >> 1, xq = (qd & 1) * 4;
            float FY[4][4], FX[4];
#pragma unroll
            for (int i = 0; i < 4; ++i) {
                int yn = 2 * i + yq;
                float gg = __shfl(invS1, yn, 64);
#pragma unroll
                for (int j = 0; j < 4; ++j) {
                    int dy = yn - (2 * j + ymb);
                    FY[i][j] = __expf(-(float)(dy * dy) * INV2S2) * gg;
                }
            }
#pragma unroll
            for (int rr = 0; rr < 4; ++rr) {
                int xn = xq + rr;
                int dx = xn - xm;
                FX[rr] = __expf(-(float)(dx * dx) * INV2S2) * __shfl(invS1, xn, 64);
            }

            const float SCALE = 0.17677669529663687f;  // 1/sqrt(32)
#pragma unroll
            for (int i = 0; i < 4; ++i)
#pragma unroll
                for (int rr = 0; rr < 4; ++rr) {
                    float lj[4];
                    float mx = -1e30f;
#pragma unroll
                    for (int j = 0; j < 4; ++j) {
                        lj[j] = s[i][j][rr] * SCALE * FY[i][j] * FX[rr];
                        mx = fmaxf(mx, lj[j]);
                    }
                    mx = fmaxf(mx, __shfl_xor(mx, 1));
                    mx = fmaxf(mx, __shfl_xor(mx, 2));
                    mx = fmaxf(mx, __shfl_xor(mx, 4));
                    mx = fmaxf(mx, __shfl_xor(mx, 8));
                    float sum = 0.f;
#pragma unroll
                    for (int j = 0; j < 4; ++j) {
                        lj[j] = __expf(lj[j] - mx);
                        sum += lj[j];
                    }
                    sum += __shfl_xor(sum, 1);
                    sum += __shfl_xor(sum, 2);
                    sum += __shfl_xor(sum, 4);
                    sum += __shfl_xor(sum, 8);
                    float inv = 1.0f / sum;
                    int n = i * 16 + qd * 4 + rr;
#pragma unroll
                    for (int j = 0; j < 4; ++j) {
                        bf16 pv = (bf16)(lj[j] * inv);
                        *(bf16*)&pw[n * 72 + j * 16 + ln] = pv;
                    }
                }
        }

        f32x4 o[4][2];
#pragma unroll
        for (int i = 0; i < 4; ++i) {
            o[i][0] = zro;
            o[i][1] = zro;
        }
#pragma unroll
        for (int kc = 0; kc < 64; kc += 32) {
            bf16x8 bv2[2];
#pragma unroll
            for (int j2 = 0; j2 < 2; ++j2) {
                int cc = j2 * 2 + (ln >> 3);
#pragma unroll
                for (int jj = 0; jj < 8; ++jj) {
                    int rv = kc + q8 + jj;
                    bv2[j2][jj] = *(const bf16*)&pw[4608 + rv * 32 +
                                                   ((cc ^ (((rv >> 3) ^ rv) & 3)) << 3) + (ln & 7)];
                }
            }
#pragma unroll
            for (int i = 0; i < 4; ++i) {
                bf16x8 ap = *(const bf16x8*)(const void*)&pw[(i * 16 + ln) * 72 + kc + q8];
#pragma unroll
                for (int j2 = 0; j2 < 2; ++j2) o[i][j2] = MFMA16(ap, bv2[j2], o[i][j2]);
            }
        }
#pragma unroll
        for (int i = 0; i < 4; ++i)
#pragma unroll
            for (int j2 = 0; j2 < 2; ++j2)
#pragma unroll
                for (int rr = 0; rr < 4; ++rr)
                    attnout[((size_t)win * 64 + i * 16 + qd * 4 + rr) * 512 +
                            hcol + j2 * 16 + ln] = (bf16)(o[i][j2][rr]);
    }
}

extern "C" void kernel_launch(void* const* d_in, const int* in_sizes, int n_in,
                              void* d_out, int out_size, void* d_ws, size_t ws_size,
                              hipStream_t stream) {
    const void* x = d_in[0];
    const void* w_qkv = d_in[1];
    const void* b_qkv = d_in[2];
    const void* w_proj = d_in[3];
    const void* b_proj = d_in[4];
    char* ws = (char*)d_ws;
    u32t* flag = (u32t*)(ws + OFF_FLAG);
    bf16* wqkvT = (bf16*)(ws + OFF_WQKVT);
    bf16* wprojT = (bf16*)(ws + OFF_WPROJT);
    float* bq = (float*)(ws + OFF_BQKV);
    float* bp = (float*)(ws + OFF_BPROJ);
    bf16* attnout = (bf16*)(ws + OFF_QKV);  // qkv never materialized; reuse region
    bf16* xb = (bf16*)(ws + OFF_XB);

    k_detect<<<1, 256, 0, stream>>>((const u16t*)x, flag);
    k_cvt<<<2048, 256, 0, stream>>>((const float*)x, xb, flag);
    k_trans<1536, true><<<dim3(24, 8), 256, 0, stream>>>(w_qkv, wqkvT, flag);
    k_trans<512, false><<<dim3(8, 8), 256, 0, stream>>>(w_proj, wprojT, flag);
    k_bias<<<8, 256, 0, stream>>>(b_qkv, b_proj, flag, ws);
    // mega: 2048 windows x 2 head-halves = 4096 blocks, barrier-free K-loop
    k_mega<<<4096, 512, 0, stream>>>(x, xb, wqkvT, bq, attnout, flag);
    // proj GEMM: [131072,512] @ [512,512] -> d_out
    k_gemm<512><<<1024, 512, 0, stream>>>((const void*)attnout, attnout, wprojT, bp, d_out, flag, 2);
}

// Round 7
// 970.272 us; speedup vs baseline: 1.1364x; 1.1364x over previous
//
#include <hip/hip_runtime.h>
#include <hip/hip_bf16.h>
#include <stdint.h>

typedef __bf16 bf16;
typedef __bf16 bf16x8 __attribute__((ext_vector_type(8)));
typedef float f32x4 __attribute__((ext_vector_type(4)));
typedef unsigned short u16t;
typedef unsigned int u32t;

#define MFMA16(a, b, c) __builtin_amdgcn_mfma_f32_16x16x32_bf16((a), (b), (c), 0, 0, 0)

typedef const void __attribute__((address_space(1))) cg_void;
typedef void __attribute__((address_space(3))) lds_void;
#define GLL16(g, l) __builtin_amdgcn_global_load_lds((cg_void*)(g), (lds_void*)(l), 16, 0, 0)
#define VWAIT(n) asm volatile("s_waitcnt vmcnt(" #n ")" ::: "memory")

// ---------------- ws layout (bytes) ----------------
#define OFF_FLAG   0
#define OFF_BQKV   256
#define OFF_BPROJ  6400
#define OFF_WQKVT  8448
#define OFF_WPROJT 1581312
#define OFF_QKV    2105600      // attn-out (134 MB; qkv never materialized, xb gone)

// head-triple permutation: reordered-W^T row n <- original qkv col src(n)
// h = n/96, r = n%96, part = r/32 (0=Q,1=K,2=V), d = r%32; src = part*512 + h*32 + d

// ---------------- dtype detector ----------------
__global__ __launch_bounds__(256) void k_detect(const u16t* x, u32t* flag) {
    __shared__ int cnt;
    if (threadIdx.x == 0) cnt = 0;
    __syncthreads();
    u16t h = x[threadIdx.x * 2];
    int e = (h >> 7) & 0xFF;
    int ok = (h == 0) || (e >= 100 && e <= 134);
    atomicAdd(&cnt, ok);
    __syncthreads();
    if (threadIdx.x == 0) flag[0] = (cnt >= 200) ? 1u : 0u;
}

// ---------------- weight transpose: W[512][N] -> Wt[N][512] bf16 ----------------
template <int N, bool PERM>
__global__ __launch_bounds__(256) void k_trans(const void* W, bf16* Wt, const u32t* flagp) {
    __shared__ float T[64][65];
    const int isbf = (int)flagp[0];
    const int n0 = blockIdx.x * 64, k0 = blockIdx.y * 64;
    const int t = threadIdx.x;
    const int lc = t & 63, lr = t >> 6;
#pragma unroll
    for (int rr = 0; rr < 16; ++rr) {
        int row = rr * 4 + lr;
        int col = n0 + lc;
        int srcc = col;
        if (PERM) {
            int h = col / 96, r = col % 96;
            srcc = (r >> 5) * 512 + h * 32 + (r & 31);
        }
        size_t g = (size_t)(k0 + row) * N + srcc;
        float v = isbf ? (float)((const bf16*)W)[g] : ((const float*)W)[g];
        T[row][lc] = v;
    }
    __syncthreads();
#pragma unroll
    for (int rr = 0; rr < 16; ++rr) {
        int row = rr * 4 + lr;
        Wt[(size_t)(n0 + row) * 512 + k0 + lc] = (bf16)T[lc][row];
    }
}

// ---------------- bias prep -> f32 (bq permuted to head-triple order) ----------
__global__ __launch_bounds__(256) void k_bias(const void* b_qkv, const void* b_proj,
                                              const u32t* flagp, char* ws) {
    float* bq = (float*)(ws + OFF_BQKV);
    float* bp = (float*)(ws + OFF_BPROJ);
    const int isbf = (int)flagp[0];
    int gid = blockIdx.x * 256 + threadIdx.x;
    if (gid < 1536) {
        int h = gid / 96, r = gid % 96;
        int src = (r >> 5) * 512 + h * 32 + (r & 31);
        bq[gid] = isbf ? (float)((const bf16*)b_qkv)[src] : ((const float*)b_qkv)[src];
    } else if (gid < 2048) {
        int o = gid - 1536;
        bp[o] = isbf ? (float)((const bf16*)b_proj)[o] : ((const float*)b_proj)[o];
    }
}

// ---------------- proj GEMM (round-3 256^2 8-phase template, unchanged) -------
template <int NTOT>
__global__ __launch_bounds__(512, 2) void k_gemm(const void* Ax, const bf16* Axb, const bf16* Bt,
                                                 const float* bias, void* Cp,
                                                 const u32t* flagp, int omode) {
    __shared__ __align__(16) u16t As[2 * 16384];
    __shared__ __align__(16) u16t Bs[2 * 16384];
    constexpr int NBN = NTOT / 256;
    const int isbf = (int)flagp[0];
    const int out_bf16 = (omode == 1) || isbf;
    const bf16* Ab = isbf ? (const bf16*)Ax : Axb;

    const int t = threadIdx.x;
    const int w = t >> 6, lane = t & 63;
    const int ln = lane & 15, qd = lane >> 4;
    const int wm = w >> 2, wn = w & 3;

    const int flat = blockIdx.x;
    const int xcd = flat & 7, slot = flat >> 3;
    const int n_idx = slot % NBN, grp = slot / NBN;
    const int m0 = (grp * 8 + xcd) * 256;
    const int n0 = n_idx * 256;

    const int l8 = lane >> 3, pc = lane & 7;
    const int cs8 = (pc ^ l8) * 8;
    u32t aoff[2][2], boff[2][2];
    int adst[2][2], bdst[2][2];
#pragma unroll
    for (int s = 0; s < 2; ++s)
#pragma unroll
        for (int q2 = 0; q2 < 2; ++q2) {
            int rA = q2 * 128 + s * 64 + w * 8;
            aoff[s][q2] = (u32t)(m0 + rA + l8) * 512 + cs8;
            adst[s][q2] = rA * 64;
            int rB = (q2 * 2 + (w >> 2)) * 64 + s * 32 + (w & 3) * 8;
            boff[s][q2] = (u32t)(n0 + rB + l8) * 512 + cs8;
            bdst[s][q2] = rB * 64;
        }

    const int p0 = (qd ^ (ln & 7)) * 8;
    int abase[4], bbase[2];
#pragma unroll
    for (int i = 0; i < 4; ++i) abase[i] = (wm * 128 + i * 16 + ln) * 64 + p0;
#pragma unroll
    for (int j = 0; j < 2; ++j) bbase[j] = (wn * 64 + j * 16 + ln) * 64 + p0;

    f32x4 acc[8][4];
    f32x4 zero = {0.f, 0.f, 0.f, 0.f};
#pragma unroll
    for (int i = 0; i < 8; ++i)
#pragma unroll
        for (int j = 0; j < 4; ++j) acc[i][j] = zero;

    auto stageA = [&](int s, int buf, int kt) {
#pragma unroll
        for (int q2 = 0; q2 < 2; ++q2)
            GLL16(Ab + aoff[s][q2] + kt * 64, &As[buf * 16384 + adst[s][q2]]);
    };
    auto stageB = [&](int s, int buf, int kt) {
#pragma unroll
        for (int q2 = 0; q2 < 2; ++q2)
            GLL16(Bt + boff[s][q2] + kt * 64, &Bs[buf * 16384 + bdst[s][q2]]);
    };

#define PH(BUF, QM, QN, STG, WAITOP)                                             \
    {                                                                            \
        bf16x8 af[4][2], bv[2][2];                                               \
        const u16t* Ap = &As[(BUF) * 16384 + (QM) * 4096];                       \
        const u16t* Bp = &Bs[(BUF) * 16384 + (QN) * 2048];                       \
        _Pragma("unroll") for (int i = 0; i < 4; ++i) {                          \
            af[i][0] = *(const bf16x8*)(const void*)&Ap[abase[i]];               \
            af[i][1] = *(const bf16x8*)(const void*)&Ap[abase[i] ^ 32];          \
        }                                                                        \
        _Pragma("unroll") for (int j = 0; j < 2; ++j) {                          \
            bv[j][0] = *(const bf16x8*)(const void*)&Bp[bbase[j]];               \
            bv[j][1] = *(const bf16x8*)(const void*)&Bp[bbase[j] ^ 32];          \
        }                                                                        \
        STG;                                                                     \
        WAITOP;                                                                  \
        __builtin_amdgcn_s_barrier();                                            \
        __builtin_amdgcn_s_setprio(1);                                           \
        _Pragma("unroll") for (int i = 0; i < 4; ++i)                            \
            _Pragma("unroll") for (int j = 0; j < 2; ++j) {                      \
                acc[(QM) * 4 + i][(QN) * 2 + j] =                                \
                    MFMA16(af[i][0], bv[j][0], acc[(QM) * 4 + i][(QN) * 2 + j]); \
                acc[(QM) * 4 + i][(QN) * 2 + j] =                                \
                    MFMA16(af[i][1], bv[j][1], acc[(QM) * 4 + i][(QN) * 2 + j]); \
            }                                                                    \
        __builtin_amdgcn_s_setprio(0);                                           \
        __builtin_amdgcn_s_barrier();                                            \
    }

    stageA(0, 0, 0);
    stageB(0, 0, 0);
    stageB(1, 0, 0);
    stageA(1, 0, 0);
    VWAIT(4);
    __builtin_amdgcn_s_barrier();

    for (int kt = 0; kt < 7; ++kt) {
        const int buf = kt & 1, nb = buf ^ 1, k1 = kt + 1;
        PH(buf, 0, 0, stageA(0, nb, k1), VWAIT(4));
        PH(buf, 0, 1, stageB(0, nb, k1), VWAIT(4));
        PH(buf, 1, 0, stageB(1, nb, k1), VWAIT(6));
        PH(buf, 1, 1, stageA(1, nb, k1), VWAIT(4));
    }
    PH(1, 0, 0, (void)0, VWAIT(2));
    PH(1, 0, 1, (void)0, VWAIT(0));
    PH(1, 1, 0, (void)0, (void)0);
    PH(1, 1, 1, (void)0, (void)0);
#undef PH

    float bj[4];
#pragma unroll
    for (int j = 0; j < 4; ++j) bj[j] = bias[n0 + wn * 64 + j * 16 + ln];

    if (out_bf16) {
        bf16* C = (bf16*)Cp;
#pragma unroll
        for (int i = 0; i < 8; ++i)
#pragma unroll
            for (int j = 0; j < 4; ++j)
#pragma unroll
                for (int rr = 0; rr < 4; ++rr) {
                    size_t row = (size_t)m0 + wm * 128 + i * 16 + qd * 4 + rr;
                    int col = n0 + wn * 64 + j * 16 + ln;
                    C[row * NTOT + col] = (bf16)(acc[i][j][rr] + bj[j]);
                }
    } else {
        float* C = (float*)Cp;
#pragma unroll
        for (int i = 0; i < 8; ++i)
#pragma unroll
            for (int j = 0; j < 4; ++j)
#pragma unroll
                for (int rr = 0; rr < 4; ++rr) {
                    size_t row = (size_t)m0 + wm * 128 + i * 16 + qd * 4 + rr;
                    int col = n0 + wn * 64 + j * 16 + ln;
                    C[row * NTOT + col] = acc[i][j][rr] + bj[j];
                }
    }
}

// ---------------- FUSE2: QKV GEMM + attention, wave = (window, head) ----------
// Block: BM=128 tokens (2 windows) x BN=192 cols (2 heads); 8192 blocks x 256 thr
// = 4 waves. Wave (wm,wn) owns GEMM tile rows wm*64, cols wn*96 -> acc[4][6] is
// the COMPLETE Q|K|V of (window win=blkm*2+wm, head g=n_idx*2+wn). LDS 80 KB
// (A 2x16KB + B 2x24KB, attn patches overlay) -> 2 blocks/CU: cross-block overlap
// at barriers. A staged from f32 x directly (T14: issue loads t+1 -> COMPUTE(t)
// -> vmcnt(0) -> cvt + swizzled ds_write) -- k_cvt/xb eliminated, same f32->bf16
// rounding. B staged GLL16 + inverse-swizzled source (R3-validated, 0-conflict).
// Stash+attention are wave-PRIVATE (no block sync after K-loop's last barrier).
// Per-acc K-accumulation order unchanged (kt 0..7, kk 0,1) -> absmax identical.
__global__ __launch_bounds__(256, 2) void k_fuse2(const void* Ax, const bf16* Bt,
                                                  const float* bias, bf16* attnout,
                                                  const u32t* flagp) {
    __shared__ __align__(16) u16t pool[40960];   // A:[0,16384) B:[16384,40960)
    const int isbf = (int)flagp[0];
    const float* Af = (const float*)Ax;
    const bf16* Abf = (const bf16*)Ax;

    const int t = threadIdx.x;
    const int w = t >> 6, lane = t & 63;
    const int ln = lane & 15, qd = lane >> 4, q8 = qd * 8;
    const int wm = w >> 1, wn = w & 1;

    const int flat = blockIdx.x;
    const int xcd = flat & 7, slot = flat >> 3;
    const int n_idx = slot & 7, mgrp = slot >> 3;
    const int blkm = mgrp * 8 + xcd;             // 0..1023 (bijective)
    const int m0 = blkm * 128;
    const int n0 = n_idx * 192;
    const int win = blkm * 2 + wm;
    const int g = n_idx * 2 + wn;

    // A staging map: thread covers row r = t>>1, half = t&1 (chunks half*4..+4)
    const int ar_row = t >> 1, ahalf = t & 1;
    const u32t arow = (u32t)(m0 + ar_row) * 512 + ahalf * 32;
    const int ar7 = ar_row & 7;

    // B staging (GLL16, inverse-swizzled source)
    const int l8 = lane >> 3;
    const int cs8 = ((lane & 7) ^ l8) * 8;
    u32t bsrc[6];
#pragma unroll
    for (int q = 0; q < 6; ++q)
        bsrc[q] = (u32t)(n0 + w * 48 + q * 8 + l8) * 512 + cs8;

    // fragment read bases (u16 idx; chunk swizzle c ^ (row&7), row&7 == ln&7)
    const int s7 = ln & 7;
    int afo[4], bfo[6];
#pragma unroll
    for (int i = 0; i < 4; ++i) afo[i] = (wm * 64 + i * 16 + ln) * 64;
#pragma unroll
    for (int j = 0; j < 6; ++j) bfo[j] = (wn * 96 + j * 16 + ln) * 64;

    f32x4 acc[4][6];
    f32x4 zero = {0.f, 0.f, 0.f, 0.f};
#pragma unroll
    for (int i = 0; i < 4; ++i)
#pragma unroll
        for (int j = 0; j < 6; ++j) acc[i][j] = zero;

    float4 ar[8];
    bf16x8 ab4[4];

    auto A_ISSUE = [&](int kt) {
        if (!isbf) {
#pragma unroll
            for (int m = 0; m < 8; ++m)
                ar[m] = *(const float4*)(Af + arow + kt * 64 + m * 4);
        } else {
#pragma unroll
            for (int cc = 0; cc < 4; ++cc)
                ab4[cc] = *(const bf16x8*)(Abf + arow + kt * 64 + cc * 8);
        }
    };
    auto A_WRITE = [&](int buf) {
#pragma unroll
        for (int cc = 0; cc < 4; ++cc) {
            int c = ahalf * 4 + cc;
            int pc = c ^ ar7;
            bf16x8 h;
            if (!isbf) {
                float4 v0 = ar[cc * 2], v1 = ar[cc * 2 + 1];
                h[0] = (bf16)v0.x; h[1] = (bf16)v0.y; h[2] = (bf16)v0.z; h[3] = (bf16)v0.w;
                h[4] = (bf16)v1.x; h[5] = (bf16)v1.y; h[6] = (bf16)v1.z; h[7] = (bf16)v1.w;
            } else {
                h = ab4[cc];
            }
            *(bf16x8*)(void*)&pool[buf * 8192 + ar_row * 64 + pc * 8] = h;
        }
    };
    auto B_STAGE = [&](int buf, int kt) {
#pragma unroll
        for (int q = 0; q < 6; ++q)
            GLL16(Bt + bsrc[q] + kt * 64, &pool[16384 + buf * 12288 + w * 3072 + q * 512]);
    };
    auto COMPUTE = [&](int buf) {
#pragma unroll
        for (int kk = 0; kk < 2; ++kk) {
            bf16x8 af[4], bv[6];
            const int cw = ((kk * 4 + qd) ^ s7) * 8;   // swizzled chunk offset (qd-dep)
            // note: swizzle must use per-chunk XOR: chunk = kk*4+qd
#pragma unroll
            for (int i = 0; i < 4; ++i)
                af[i] = *(const bf16x8*)(const void*)&pool[buf * 8192 + afo[i] + cw];
#pragma unroll
            for (int j = 0; j < 6; ++j)
                bv[j] = *(const bf16x8*)(const void*)&pool[16384 + buf * 12288 + bfo[j] + cw];
            __builtin_amdgcn_s_setprio(1);
#pragma unroll
            for (int i = 0; i < 4; ++i)
#pragma unroll
                for (int j = 0; j < 6; ++j)
                    acc[i][j] = MFMA16(af[i], bv[j], acc[i][j]);
            __builtin_amdgcn_s_setprio(0);
        }
    };

    // prologue: tile 0
    A_ISSUE(0);
    B_STAGE(0, 0);
    VWAIT(0);
    A_WRITE(0);
    __syncthreads();
    // T14 2-phase: issue t+1 loads, compute t, drain, write A(t+1), barrier
    for (int kt = 0; kt < 8; ++kt) {
        const int buf = kt & 1, nb = buf ^ 1;
        if (kt < 7) {
            A_ISSUE(kt + 1);
            B_STAGE(nb, kt + 1);
        }
        COMPUTE(buf);
        if (kt < 7) {
            VWAIT(0);
            A_WRITE(nb);
        }
        __syncthreads();
    }

    // ---- stash Q,K,V (+bias) into the wave's PRIVATE patch (no block sync) ----
    float bj[6];
#pragma unroll
    for (int j = 0; j < 6; ++j) bj[j] = bias[g * 96 + j * 16 + ln];
    u16t* pw = &pool[w * 6656];
#pragma unroll
    for (int i = 0; i < 4; ++i)
#pragma unroll
        for (int j = 0; j < 6; ++j) {
            int part = j >> 1;                     // 0=Q 1=K 2=V
            int d = (j & 1) * 16 + ln;
#pragma unroll
            for (int rr = 0; rr < 4; ++rr) {
                int tok = i * 16 + qd * 4 + rr;
                bf16 val = (bf16)(acc[i][j][rr] + bj[j]);
                int idx;
                if (part == 2)
                    idx = 4608 + tok * 32 +
                          (((d >> 3) ^ (((tok >> 3) ^ tok) & 3)) << 3) + (d & 7);
                else
                    idx = part * 2048 + tok * 32 +
                          (((d >> 3) ^ ((tok >> 1) & 3)) << 3) + (d & 7);
                *(bf16*)&pw[idx] = val;
            }
        }

    // ---- attention for (win, head g): verbatim validated math ----
    {
        const int hcol = g * 32;
        const int qswz = (qd ^ ((ln >> 1) & 3)) * 8;

        bf16x8 aq[4], bk[4];
#pragma unroll
        for (int i = 0; i < 4; ++i)
            aq[i] = *(const bf16x8*)(const void*)&pw[(i * 16 + ln) * 32 + qswz];
#pragma unroll
        for (int j = 0; j < 4; ++j)
            bk[j] = *(const bf16x8*)(const void*)&pw[2048 + (j * 16 + ln) * 32 + qswz];

        f32x4 zro = {0.f, 0.f, 0.f, 0.f};
        f32x4 s[4][4];
#pragma unroll
        for (int i = 0; i < 4; ++i)
#pragma unroll
            for (int j = 0; j < 4; ++j) s[i][j] = MFMA16(aq[i], bk[j], zro);

        const float INV2S2 = 3.28731097961867f;  // 1/(2*0.39^2)
        {
            int c = lane & 7;
            float S1 = 0.f;
#pragma unroll
            for (int c2 = 0; c2 < 8; ++c2) {
                int dd = c - c2;
                S1 += __expf(-(float)(dd * dd) * INV2S2);
            }
            float invS1 = 1.0f / S1;
            const int ymb = ln >> 3, xm = ln & 7, yq = qd >> 1, xq = (qd & 1) * 4;
            float FY[4][4], FX[4];
#pragma unroll
            for (int i = 0; i < 4; ++i) {
                int yn = 2 * i + yq;
                float gg = __shfl(invS1, yn, 64);
#pragma unroll
                for (int j = 0; j < 4; ++j) {
                    int dy = yn - (2 * j + ymb);
                    FY[i][j] = __expf(-(float)(dy * dy) * INV2S2) * gg;
                }
            }
#pragma unroll
            for (int rr = 0; rr < 4; ++rr) {
                int xn = xq + rr;
                int dx = xn - xm;
                FX[rr] = __expf(-(float)(dx * dx) * INV2S2) * __shfl(invS1, xn, 64);
            }

            const float SCALE = 0.17677669529663687f;  // 1/sqrt(32)
#pragma unroll
            for (int i = 0; i < 4; ++i)
#pragma unroll
                for (int rr = 0; rr < 4; ++rr) {
                    float lj[4];
                    float mx = -1e30f;
#pragma unroll
                    for (int j = 0; j < 4; ++j) {
                        lj[j] = s[i][j][rr] * SCALE * FY[i][j] * FX[rr];
                        mx = fmaxf(mx, lj[j]);
                    }
                    mx = fmaxf(mx, __shfl_xor(mx, 1));
                    mx = fmaxf(mx, __shfl_xor(mx, 2));
                    mx = fmaxf(mx, __shfl_xor(mx, 4));
                    mx = fmaxf(mx, __shfl_xor(mx, 8));
                    float sum = 0.f;
#pragma unroll
                    for (int j = 0; j < 4; ++j) {
                        lj[j] = __expf(lj[j] - mx);
                        sum += lj[j];
                    }
                    sum += __shfl_xor(sum, 1);
                    sum += __shfl_xor(sum, 2);
                    sum += __shfl_xor(sum, 4);
                    sum += __shfl_xor(sum, 8);
                    float inv = 1.0f / sum;
                    int n = i * 16 + qd * 4 + rr;
#pragma unroll
                    for (int j = 0; j < 4; ++j) {
                        bf16 pv = (bf16)(lj[j] * inv);
                        *(bf16*)&pw[n * 72 + j * 16 + ln] = pv;
                    }
                }
        }

        f32x4 o[4][2];
#pragma unroll
        for (int i = 0; i < 4; ++i) {
            o[i][0] = zro;
            o[i][1] = zro;
        }
#pragma unroll
        for (int kc = 0; kc < 64; kc += 32) {
            bf16x8 bv2[2];
#pragma unroll
            for (int j2 = 0; j2 < 2; ++j2) {
                int cc = j2 * 2 + (ln >> 3);
#pragma unroll
                for (int jj = 0; jj < 8; ++jj) {
                    int rv = kc + q8 + jj;
                    bv2[j2][jj] = *(const bf16*)&pw[4608 + rv * 32 +
                                                   ((cc ^ (((rv >> 3) ^ rv) & 3)) << 3) + (ln & 7)];
                }
            }
#pragma unroll
            for (int i = 0; i < 4; ++i) {
                bf16x8 ap = *(const bf16x8*)(const void*)&pw[(i * 16 + ln) * 72 + kc + q8];
#pragma unroll
                for (int j2 = 0; j2 < 2; ++j2) o[i][j2] = MFMA16(ap, bv2[j2], o[i][j2]);
            }
        }
#pragma unroll
        for (int i = 0; i < 4; ++i)
#pragma unroll
            for (int j2 = 0; j2 < 2; ++j2)
#pragma unroll
                for (int rr = 0; rr < 4; ++rr)
                    attnout[((size_t)win * 64 + i * 16 + qd * 4 + rr) * 512 +
                            hcol + j2 * 16 + ln] = (bf16)(o[i][j2][rr]);
    }
}

extern "C" void kernel_launch(void* const* d_in, const int* in_sizes, int n_in,
                              void* d_out, int out_size, void* d_ws, size_t ws_size,
                              hipStream_t stream) {
    const void* x = d_in[0];
    const void* w_qkv = d_in[1];
    const void* b_qkv = d_in[2];
    const void* w_proj = d_in[3];
    const void* b_proj = d_in[4];
    char* ws = (char*)d_ws;
    u32t* flag = (u32t*)(ws + OFF_FLAG);
    bf16* wqkvT = (bf16*)(ws + OFF_WQKVT);
    bf16* wprojT = (bf16*)(ws + OFF_WPROJT);
    float* bq = (float*)(ws + OFF_BQKV);
    float* bp = (float*)(ws + OFF_BPROJ);
    bf16* attnout = (bf16*)(ws + OFF_QKV);

    k_detect<<<1, 256, 0, stream>>>((const u16t*)x, flag);
    k_trans<1536, true><<<dim3(24, 8), 256, 0, stream>>>(w_qkv, wqkvT, flag);
    k_trans<512, false><<<dim3(8, 8), 256, 0, stream>>>(w_proj, wprojT, flag);
    k_bias<<<8, 256, 0, stream>>>(b_qkv, b_proj, flag, ws);
    // fused QKV GEMM + attention: 1024 m-blocks x 8 head-pair blocks, 4 waves ea.
    k_fuse2<<<8192, 256, 0, stream>>>(x, wqkvT, bq, attnout, flag);
    // proj GEMM: [131072,512] @ [512,512] -> d_out
    k_gemm<512><<<1024, 512, 0, stream>>>((const void*)attnout, attnout, wprojT, bp, d_out, flag, 2);
}

// Round 8
// 886.859 us; speedup vs baseline: 1.2433x; 1.0941x over previous
//
#include <hip/hip_runtime.h>
#include <hip/hip_bf16.h>
#include <stdint.h>

typedef __bf16 bf16;
typedef __bf16 bf16x8 __attribute__((ext_vector_type(8)));
typedef float f32x4 __attribute__((ext_vector_type(4)));
typedef unsigned short u16t;
typedef unsigned int u32t;

#define MFMA16(a, b, c) __builtin_amdgcn_mfma_f32_16x16x32_bf16((a), (b), (c), 0, 0, 0)

typedef const void __attribute__((address_space(1))) cg_void;
typedef void __attribute__((address_space(3))) lds_void;
#define GLL16(g, l) __builtin_amdgcn_global_load_lds((cg_void*)(g), (lds_void*)(l), 16, 0, 0)
#define VWAIT(n) asm volatile("s_waitcnt vmcnt(" #n ")" ::: "memory")

// ---------------- ws layout (bytes) ----------------
#define OFF_FLAG   0
#define OFF_BQKV   256
#define OFF_BPROJ  6400
#define OFF_WQKVT  8448
#define OFF_WPROJT 1581312
#define OFF_QKV    2105600      // attn-out (134 MB; qkv never materialized)
#define OFF_XB     404758784    // xb (bf16 x, 134 MB)

// head-triple permutation: reordered-W^T row n <- original qkv col src(n)
// h = n/96, r = n%96, part = r/32 (0=Q,1=K,2=V), d = r%32; src = part*512 + h*32 + d

// ---------------- dtype detector ----------------
__global__ __launch_bounds__(256) void k_detect(const u16t* x, u32t* flag) {
    __shared__ int cnt;
    if (threadIdx.x == 0) cnt = 0;
    __syncthreads();
    u16t h = x[threadIdx.x * 2];
    int e = (h >> 7) & 0xFF;
    int ok = (h == 0) || (e >= 100 && e <= 134);
    atomicAdd(&cnt, ok);
    __syncthreads();
    if (threadIdx.x == 0) flag[0] = (cnt >= 200) ? 1u : 0u;
}

// ---------------- x f32 -> bf16 pre-pass (skipped when input already bf16) ----
__global__ __launch_bounds__(256) void k_cvt(const float* x, bf16* xb, const u32t* flagp) {
    if (flagp[0]) return;
    const size_t TOT = (size_t)131072 * 512;
    size_t i = (size_t)(blockIdx.x * 256 + threadIdx.x) * 8;
    const size_t stride = (size_t)gridDim.x * 256 * 8;
    for (; i < TOT; i += stride) {
        float4 v0 = *(const float4*)(x + i);
        float4 v1 = *(const float4*)(x + i + 4);
        bf16x8 h;
        h[0] = (bf16)v0.x; h[1] = (bf16)v0.y; h[2] = (bf16)v0.z; h[3] = (bf16)v0.w;
        h[4] = (bf16)v1.x; h[5] = (bf16)v1.y; h[6] = (bf16)v1.z; h[7] = (bf16)v1.w;
        *(bf16x8*)(xb + i) = h;
    }
}

// ---------------- weight transpose: W[512][N] -> Wt[N][512] bf16 ----------------
template <int N, bool PERM>
__global__ __launch_bounds__(256) void k_trans(const void* W, bf16* Wt, const u32t* flagp) {
    __shared__ float T[64][65];
    const int isbf = (int)flagp[0];
    const int n0 = blockIdx.x * 64, k0 = blockIdx.y * 64;
    const int t = threadIdx.x;
    const int lc = t & 63, lr = t >> 6;
#pragma unroll
    for (int rr = 0; rr < 16; ++rr) {
        int row = rr * 4 + lr;
        int col = n0 + lc;
        int srcc = col;
        if (PERM) {
            int h = col / 96, r = col % 96;
            srcc = (r >> 5) * 512 + h * 32 + (r & 31);
        }
        size_t g = (size_t)(k0 + row) * N + srcc;
        float v = isbf ? (float)((const bf16*)W)[g] : ((const float*)W)[g];
        T[row][lc] = v;
    }
    __syncthreads();
#pragma unroll
    for (int rr = 0; rr < 16; ++rr) {
        int row = rr * 4 + lr;
        Wt[(size_t)(n0 + row) * 512 + k0 + lc] = (bf16)T[lc][row];
    }
}

// ---------------- bias prep -> f32 (bq permuted to head-triple order) ----------
__global__ __launch_bounds__(256) void k_bias(const void* b_qkv, const void* b_proj,
                                              const u32t* flagp, char* ws) {
    float* bq = (float*)(ws + OFF_BQKV);
    float* bp = (float*)(ws + OFF_BPROJ);
    const int isbf = (int)flagp[0];
    int gid = blockIdx.x * 256 + threadIdx.x;
    if (gid < 1536) {
        int h = gid / 96, r = gid % 96;
        int src = (r >> 5) * 512 + h * 32 + (r & 31);
        bq[gid] = isbf ? (float)((const bf16*)b_qkv)[src] : ((const float*)b_qkv)[src];
    } else if (gid < 2048) {
        int o = gid - 1536;
        bp[o] = isbf ? (float)((const bf16*)b_proj)[o] : ((const float*)b_proj)[o];
    }
}

// ---------------- proj GEMM (round-3 256^2 8-phase template, unchanged) -------
template <int NTOT>
__global__ __launch_bounds__(512, 2) void k_gemm(const void* Ax, const bf16* Axb, const bf16* Bt,
                                                 const float* bias, void* Cp,
                                                 const u32t* flagp, int omode) {
    __shared__ __align__(16) u16t As[2 * 16384];
    __shared__ __align__(16) u16t Bs[2 * 16384];
    constexpr int NBN = NTOT / 256;
    const int isbf = (int)flagp[0];
    const int out_bf16 = (omode == 1) || isbf;
    const bf16* Ab = isbf ? (const bf16*)Ax : Axb;

    const int t = threadIdx.x;
    const int w = t >> 6, lane = t & 63;
    const int ln = lane & 15, qd = lane >> 4;
    const int wm = w >> 2, wn = w & 3;

    const int flat = blockIdx.x;
    const int xcd = flat & 7, slot = flat >> 3;
    const int n_idx = slot % NBN, grp = slot / NBN;
    const int m0 = (grp * 8 + xcd) * 256;
    const int n0 = n_idx * 256;

    const int l8 = lane >> 3, pc = lane & 7;
    const int cs8 = (pc ^ l8) * 8;
    u32t aoff[2][2], boff[2][2];
    int adst[2][2], bdst[2][2];
#pragma unroll
    for (int s = 0; s < 2; ++s)
#pragma unroll
        for (int q2 = 0; q2 < 2; ++q2) {
            int rA = q2 * 128 + s * 64 + w * 8;
            aoff[s][q2] = (u32t)(m0 + rA + l8) * 512 + cs8;
            adst[s][q2] = rA * 64;
            int rB = (q2 * 2 + (w >> 2)) * 64 + s * 32 + (w & 3) * 8;
            boff[s][q2] = (u32t)(n0 + rB + l8) * 512 + cs8;
            bdst[s][q2] = rB * 64;
        }

    const int p0 = (qd ^ (ln & 7)) * 8;
    int abase[4], bbase[2];
#pragma unroll
    for (int i = 0; i < 4; ++i) abase[i] = (wm * 128 + i * 16 + ln) * 64 + p0;
#pragma unroll
    for (int j = 0; j < 2; ++j) bbase[j] = (wn * 64 + j * 16 + ln) * 64 + p0;

    f32x4 acc[8][4];
    f32x4 zero = {0.f, 0.f, 0.f, 0.f};
#pragma unroll
    for (int i = 0; i < 8; ++i)
#pragma unroll
        for (int j = 0; j < 4; ++j) acc[i][j] = zero;

    auto stageA = [&](int s, int buf, int kt) {
#pragma unroll
        for (int q2 = 0; q2 < 2; ++q2)
            GLL16(Ab + aoff[s][q2] + kt * 64, &As[buf * 16384 + adst[s][q2]]);
    };
    auto stageB = [&](int s, int buf, int kt) {
#pragma unroll
        for (int q2 = 0; q2 < 2; ++q2)
            GLL16(Bt + boff[s][q2] + kt * 64, &Bs[buf * 16384 + bdst[s][q2]]);
    };

#define PH(BUF, QM, QN, STG, WAITOP)                                             \
    {                                                                            \
        bf16x8 af[4][2], bv[2][2];                                               \
        const u16t* Ap = &As[(BUF) * 16384 + (QM) * 4096];                       \
        const u16t* Bp = &Bs[(BUF) * 16384 + (QN) * 2048];                       \
        _Pragma("unroll") for (int i = 0; i < 4; ++i) {                          \
            af[i][0] = *(const bf16x8*)(const void*)&Ap[abase[i]];               \
            af[i][1] = *(const bf16x8*)(const void*)&Ap[abase[i] ^ 32];          \
        }                                                                        \
        _Pragma("unroll") for (int j = 0; j < 2; ++j) {                          \
            bv[j][0] = *(const bf16x8*)(const void*)&Bp[bbase[j]];               \
            bv[j][1] = *(const bf16x8*)(const void*)&Bp[bbase[j] ^ 32];          \
        }                                                                        \
        STG;                                                                     \
        WAITOP;                                                                  \
        __builtin_amdgcn_s_barrier();                                            \
        __builtin_amdgcn_s_setprio(1);                                           \
        _Pragma("unroll") for (int i = 0; i < 4; ++i)                            \
            _Pragma("unroll") for (int j = 0; j < 2; ++j) {                      \
                acc[(QM) * 4 + i][(QN) * 2 + j] =                                \
                    MFMA16(af[i][0], bv[j][0], acc[(QM) * 4 + i][(QN) * 2 + j]); \
                acc[(QM) * 4 + i][(QN) * 2 + j] =                                \
                    MFMA16(af[i][1], bv[j][1], acc[(QM) * 4 + i][(QN) * 2 + j]); \
            }                                                                    \
        __builtin_amdgcn_s_setprio(0);                                           \
        __builtin_amdgcn_s_barrier();                                            \
    }

    stageA(0, 0, 0);
    stageB(0, 0, 0);
    stageB(1, 0, 0);
    stageA(1, 0, 0);
    VWAIT(4);
    __builtin_amdgcn_s_barrier();

    for (int kt = 0; kt < 7; ++kt) {
        const int buf = kt & 1, nb = buf ^ 1, k1 = kt + 1;
        PH(buf, 0, 0, stageA(0, nb, k1), VWAIT(4));
        PH(buf, 0, 1, stageB(0, nb, k1), VWAIT(4));
        PH(buf, 1, 0, stageB(1, nb, k1), VWAIT(6));
        PH(buf, 1, 1, stageA(1, nb, k1), VWAIT(4));
    }
    PH(1, 0, 0, (void)0, VWAIT(2));
    PH(1, 0, 1, (void)0, VWAIT(0));
    PH(1, 1, 0, (void)0, (void)0);
    PH(1, 1, 1, (void)0, (void)0);
#undef PH

    float bj[4];
#pragma unroll
    for (int j = 0; j < 4; ++j) bj[j] = bias[n0 + wn * 64 + j * 16 + ln];

    if (out_bf16) {
        bf16* C = (bf16*)Cp;
#pragma unroll
        for (int i = 0; i < 8; ++i)
#pragma unroll
            for (int j = 0; j < 4; ++j)
#pragma unroll
                for (int rr = 0; rr < 4; ++rr) {
                    size_t row = (size_t)m0 + wm * 128 + i * 16 + qd * 4 + rr;
                    int col = n0 + wn * 64 + j * 16 + ln;
                    C[row * NTOT + col] = (bf16)(acc[i][j][rr] + bj[j]);
                }
    } else {
        float* C = (float*)Cp;
#pragma unroll
        for (int i = 0; i < 8; ++i)
#pragma unroll
            for (int j = 0; j < 4; ++j)
#pragma unroll
                for (int rr = 0; rr < 4; ++rr) {
                    size_t row = (size_t)m0 + wm * 128 + i * 16 + qd * 4 + rr;
                    int col = n0 + wn * 64 + j * 16 + ln;
                    C[row * NTOT + col] = acc[i][j][rr] + bj[j];
                }
    }
}

// ---------------- FUSE3: QKV GEMM + attention (R7 geometry, R5 staging) --------
// Block: BM=128 (2 windows) x BN=192 (2 heads); 8192 blocks x 256 thr = 4 waves.
// Wave (wm,wn) owns (win, head g) completely: acc[4][6] = full Q|K|V triple.
// LDS 80 KB (A 2x16KB + B 2x24KB; attn patches overlay) -> 2 blocks/CU.
// Both A (bf16 xb) and B staged via GLL16 + inverse-swizzled source.
// 4-phase/tile counted-vmcnt ledger (10 loads/wave/tile = 4A+3BL+3BH):
//   P0: read A.kk0+Bjlo.kk0 | issue A(t+1)   | VWAIT(4)  (ensures Bjhi(t))
//   P1: read Bjhi.kk0       | issue Bjlo(t+1)| -
//   P2: read A.kk1+Bjlo.kk1 | issue Bjhi(t+1)| -
//   P3: read Bjhi.kk1       | -              | VWAIT(3)  (ensures A,Bjlo(t+1))
// Never drains mid-loop (tail: P0(7)=VWAIT(0)). Each phase: 12 MFMA, 2 barriers.
// Write-hazards: every stage targets the buffer last read >=2 barriers earlier.
// Per-acc K-accumulation order unchanged (kt asc, kk asc) -> absmax identical.
__global__ __launch_bounds__(256, 2) void k_fuse3(const void* Ax, const bf16* Axb,
                                                  const bf16* Bt, const float* bias,
                                                  bf16* attnout, const u32t* flagp) {
    __shared__ __align__(16) u16t pool[40960];   // A:[0,16384) 2x8192; B:[16384,40960) 2x12288
    const int isbf = (int)flagp[0];
    const bf16* Ab = isbf ? (const bf16*)Ax : Axb;

    const int t = threadIdx.x;
    const int w = t >> 6, lane = t & 63;
    const int ln = lane & 15, qd = lane >> 4, q8 = qd * 8;
    const int wm = w >> 1, wn = w & 1;

    const int flat = blockIdx.x;
    const int xcd = flat & 7, slot = flat >> 3;
    const int n_idx = slot & 7, mgrp = slot >> 3;
    const int blkm = mgrp * 8 + xcd;             // 0..1023 (bijective)
    const int m0 = blkm * 128;
    const int n0 = n_idx * 192;
    const int win = blkm * 2 + wm;
    const int g = n_idx * 2 + wn;

    const int l8 = lane >> 3;
    const int cs8 = ((lane & 7) ^ l8) * 8;       // inverse-swizzled source chunk

    // A staging: wave w rows [w*32, w*32+32), 4 GLL16 x 8 rows
    u32t asrc[4];
    int adst[4];
#pragma unroll
    for (int q = 0; q < 4; ++q) {
        int r0 = w * 32 + q * 8;
        asrc[q] = (u32t)(m0 + r0 + l8) * 512 + cs8;
        adst[q] = r0 * 64;
    }
    // B staging: jlo rows [0,48)u[96,144), jhi = +48; 12 GLL16 each, 3/wave
    u32t blsrc[3], bhsrc[3];
    int bldst[3], bhdst[3];
#pragma unroll
    for (int k = 0; k < 3; ++k) {
        int q = 3 * w + k;
        int rl = (q < 6) ? q * 8 : 96 + (q - 6) * 8;
        int rh = rl + 48;
        blsrc[k] = (u32t)(n0 + rl + l8) * 512 + cs8;
        bldst[k] = rl * 64;
        bhsrc[k] = (u32t)(n0 + rh + l8) * 512 + cs8;
        bhdst[k] = rh * 64;
    }

    // fragment read bases (u16 idx); chunk kk*4+qd, phys = chunk ^ (row&7)=ln&7
    const int s7 = ln & 7;
    const int ck0 = ((qd) ^ s7) * 8;
    const int ck1 = ((4 + qd) ^ s7) * 8;
    int afo[4], bfo[6];
#pragma unroll
    for (int i = 0; i < 4; ++i) afo[i] = (wm * 64 + i * 16 + ln) * 64;
#pragma unroll
    for (int j = 0; j < 6; ++j) bfo[j] = (wn * 96 + j * 16 + ln) * 64;

    f32x4 acc[4][6];
    f32x4 zero = {0.f, 0.f, 0.f, 0.f};
#pragma unroll
    for (int i = 0; i < 4; ++i)
#pragma unroll
        for (int j = 0; j < 6; ++j) acc[i][j] = zero;

    auto ST_A = [&](int buf, int kt) {
#pragma unroll
        for (int q = 0; q < 4; ++q)
            GLL16(Ab + asrc[q] + kt * 64, &pool[buf * 8192 + adst[q]]);
    };
    auto ST_BL = [&](int buf, int kt) {
#pragma unroll
        for (int k = 0; k < 3; ++k)
            GLL16(Bt + blsrc[k] + kt * 64, &pool[16384 + buf * 12288 + bldst[k]]);
    };
    auto ST_BH = [&](int buf, int kt) {
#pragma unroll
        for (int k = 0; k < 3; ++k)
            GLL16(Bt + bhsrc[k] + kt * 64, &pool[16384 + buf * 12288 + bhdst[k]]);
    };

    // prologue: tile 0 (issue order A, BL, BH); need A+BL before P0 -> VWAIT(3)
    ST_A(0, 0);
    ST_BL(0, 0);
    ST_BH(0, 0);
    VWAIT(3);
    __builtin_amdgcn_s_barrier();

    for (int kt = 0; kt < 8; ++kt) {
        const int buf = kt & 1, nb = buf ^ 1;
        const u16t* Abuf = &pool[buf * 8192];
        const u16t* Bbuf = &pool[16384 + buf * 12288];
        bf16x8 af[4], bl[3], bh[3];

        // ---- P0: A.kk0 + Bjlo.kk0 ----
#pragma unroll
        for (int i = 0; i < 4; ++i)
            af[i] = *(const bf16x8*)(const void*)&Abuf[afo[i] + ck0];
#pragma unroll
        for (int j = 0; j < 3; ++j)
            bl[j] = *(const bf16x8*)(const void*)&Bbuf[bfo[j] + ck0];
        if (kt < 7) { ST_A(nb, kt + 1); VWAIT(4); }
        else VWAIT(0);
        __builtin_amdgcn_s_barrier();
        __builtin_amdgcn_s_setprio(1);
#pragma unroll
        for (int i = 0; i < 4; ++i)
#pragma unroll
            for (int j = 0; j < 3; ++j) acc[i][j] = MFMA16(af[i], bl[j], acc[i][j]);
        __builtin_amdgcn_s_setprio(0);
        __builtin_amdgcn_s_barrier();

        // ---- P1: Bjhi.kk0 (A frags reused) ----
#pragma unroll
        for (int j = 0; j < 3; ++j)
            bh[j] = *(const bf16x8*)(const void*)&Bbuf[bfo[3 + j] + ck0];
        if (kt < 7) ST_BL(nb, kt + 1);
        __builtin_amdgcn_s_barrier();
        __builtin_amdgcn_s_setprio(1);
#pragma unroll
        for (int i = 0; i < 4; ++i)
#pragma unroll
            for (int j = 0; j < 3; ++j) acc[i][3 + j] = MFMA16(af[i], bh[j], acc[i][3 + j]);
        __builtin_amdgcn_s_setprio(0);
        __builtin_amdgcn_s_barrier();

        // ---- P2: A.kk1 + Bjlo.kk1 ----
#pragma unroll
        for (int i = 0; i < 4; ++i)
            af[i] = *(const bf16x8*)(const void*)&Abuf[afo[i] + ck1];
#pragma unroll
        for (int j = 0; j < 3; ++j)
            bl[j] = *(const bf16x8*)(const void*)&Bbuf[bfo[j] + ck1];
        if (kt < 7) ST_BH(nb, kt + 1);
        __builtin_amdgcn_s_barrier();
        __builtin_amdgcn_s_setprio(1);
#pragma unroll
        for (int i = 0; i < 4; ++i)
#pragma unroll
            for (int j = 0; j < 3; ++j) acc[i][j] = MFMA16(af[i], bl[j], acc[i][j]);
        __builtin_amdgcn_s_setprio(0);
        __builtin_amdgcn_s_barrier();

        // ---- P3: Bjhi.kk1 ----
#pragma unroll
        for (int j = 0; j < 3; ++j)
            bh[j] = *(const bf16x8*)(const void*)&Bbuf[bfo[3 + j] + ck1];
        if (kt < 7) VWAIT(3);
        __builtin_amdgcn_s_barrier();
        __builtin_amdgcn_s_setprio(1);
#pragma unroll
        for (int i = 0; i < 4; ++i)
#pragma unroll
            for (int j = 0; j < 3; ++j) acc[i][3 + j] = MFMA16(af[i], bh[j], acc[i][3 + j]);
        __builtin_amdgcn_s_setprio(0);
        __builtin_amdgcn_s_barrier();
    }

    // ---- stash Q,K,V (+bias) into the wave's PRIVATE patch (no block sync) ----
    float bj[6];
#pragma unroll
    for (int j = 0; j < 6; ++j) bj[j] = bias[g * 96 + j * 16 + ln];
    u16t* pw = &pool[w * 6656];
#pragma unroll
    for (int i = 0; i < 4; ++i)
#pragma unroll
        for (int j = 0; j < 6; ++j) {
            int part = j >> 1;                     // 0=Q 1=K 2=V
            int d = (j & 1) * 16 + ln;
#pragma unroll
            for (int rr = 0; rr < 4; ++rr) {
                int tok = i * 16 + qd * 4 + rr;
                bf16 val = (bf16)(acc[i][j][rr] + bj[j]);
                int idx;
                if (part == 2)
                    idx = 4608 + tok * 32 +
                          (((d >> 3) ^ (((tok >> 3) ^ tok) & 3)) << 3) + (d & 7);
                else
                    idx = part * 2048 + tok * 32 +
                          (((d >> 3) ^ ((tok >> 1) & 3)) << 3) + (d & 7);
                *(bf16*)&pw[idx] = val;
            }
        }

    // ---- attention for (win, head g): verbatim validated math ----
    {
        const int hcol = g * 32;
        const int qswz = (qd ^ ((ln >> 1) & 3)) * 8;

        bf16x8 aq[4], bk[4];
#pragma unroll
        for (int i = 0; i < 4; ++i)
            aq[i] = *(const bf16x8*)(const void*)&pw[(i * 16 + ln) * 32 + qswz];
#pragma unroll
        for (int j = 0; j < 4; ++j)
            bk[j] = *(const bf16x8*)(const void*)&pw[2048 + (j * 16 + ln) * 32 + qswz];

        f32x4 zro = {0.f, 0.f, 0.f, 0.f};
        f32x4 s[4][4];
#pragma unroll
        for (int i = 0; i < 4; ++i)
#pragma unroll
            for (int j = 0; j < 4; ++j) s[i][j] = MFMA16(aq[i], bk[j], zro);

        const float INV2S2 = 3.28731097961867f;  // 1/(2*0.39^2)
        {
            int c = lane & 7;
            float S1 = 0.f;
#pragma unroll
            for (int c2 = 0; c2 < 8; ++c2) {
                int dd = c - c2;
                S1 += __expf(-(float)(dd * dd) * INV2S2);
            }
            float invS1 = 1.0f / S1;
            const int ymb = ln >> 3, xm = ln & 7, yq = qd >> 1, xq = (qd & 1) * 4;
            float FY[4][4], FX[4];
#pragma unroll
            for (int i = 0; i < 4; ++i) {
                int yn = 2 * i + yq;
                float gg = __shfl(invS1, yn, 64);
#pragma unroll
                for (int j = 0; j < 4; ++j) {
                    int dy = yn - (2 * j + ymb);
                    FY[i][j] = __expf(-(float)(dy * dy) * INV2S2) * gg;
                }
            }
#pragma unroll
            for (int rr = 0; rr < 4; ++rr) {
                int xn = xq + rr;
                int dx = xn - xm;
                FX[rr] = __expf(-(float)(dx * dx) * INV2S2) * __shfl(invS1, xn, 64);
            }

            const float SCALE = 0.17677669529663687f;  // 1/sqrt(32)
#pragma unroll
            for (int i = 0; i < 4; ++i)
#pragma unroll
                for (int rr = 0; rr < 4; ++rr) {
                    float lj[4];
                    float mx = -1e30f;
#pragma unroll
                    for (int j = 0; j < 4; ++j) {
                        lj[j] = s[i][j][rr] * SCALE * FY[i][j] * FX[rr];
                        mx = fmaxf(mx, lj[j]);
                    }
                    mx = fmaxf(mx, __shfl_xor(mx, 1));
                    mx = fmaxf(mx, __shfl_xor(mx, 2));
                    mx = fmaxf(mx, __shfl_xor(mx, 4));
                    mx = fmaxf(mx, __shfl_xor(mx, 8));
                    float sum = 0.f;
#pragma unroll
                    for (int j = 0; j < 4; ++j) {
                        lj[j] = __expf(lj[j] - mx);
                        sum += lj[j];
                    }
                    sum += __shfl_xor(sum, 1);
                    sum += __shfl_xor(sum, 2);
                    sum += __shfl_xor(sum, 4);
                    sum += __shfl_xor(sum, 8);
                    float inv = 1.0f / sum;
                    int n = i * 16 + qd * 4 + rr;
#pragma unroll
                    for (int j = 0; j < 4; ++j) {
                        bf16 pv = (bf16)(lj[j] * inv);
                        *(bf16*)&pw[n * 72 + j * 16 + ln] = pv;
                    }
                }
        }

        f32x4 o[4][2];
#pragma unroll
        for (int i = 0; i < 4; ++i) {
            o[i][0] = zro;
            o[i][1] = zro;
        }
#pragma unroll
        for (int kc = 0; kc < 64; kc += 32) {
            bf16x8 bv2[2];
#pragma unroll
            for (int j2 = 0; j2 < 2; ++j2) {
                int cc = j2 * 2 + (ln >> 3);
#pragma unroll
                for (int jj = 0; jj < 8; ++jj) {
                    int rv = kc + q8 + jj;
                    bv2[j2][jj] = *(const bf16*)&pw[4608 + rv * 32 +
                                                   ((cc ^ (((rv >> 3) ^ rv) & 3)) << 3) + (ln & 7)];
                }
            }
#pragma unroll
            for (int i = 0; i < 4; ++i) {
                bf16x8 ap = *(const bf16x8*)(const void*)&pw[(i * 16 + ln) * 72 + kc + q8];
#pragma unroll
                for (int j2 = 0; j2 < 2; ++j2) o[i][j2] = MFMA16(ap, bv2[j2], o[i][j2]);
            }
        }
#pragma unroll
        for (int i = 0; i < 4; ++i)
#pragma unroll
            for (int j2 = 0; j2 < 2; ++j2)
#pragma unroll
                for (int rr = 0; rr < 4; ++rr)
                    attnout[((size_t)win * 64 + i * 16 + qd * 4 + rr) * 512 +
                            hcol + j2 * 16 + ln] = (bf16)(o[i][j2][rr]);
    }
}

extern "C" void kernel_launch(void* const* d_in, const int* in_sizes, int n_in,
                              void* d_out, int out_size, void* d_ws, size_t ws_size,
                              hipStream_t stream) {
    const void* x = d_in[0];
    const void* w_qkv = d_in[1];
    const void* b_qkv = d_in[2];
    const void* w_proj = d_in[3];
    const void* b_proj = d_in[4];
    char* ws = (char*)d_ws;
    u32t* flag = (u32t*)(ws + OFF_FLAG);
    bf16* wqkvT = (bf16*)(ws + OFF_WQKVT);
    bf16* wprojT = (bf16*)(ws + OFF_WPROJT);
    float* bq = (float*)(ws + OFF_BQKV);
    float* bp = (float*)(ws + OFF_BPROJ);
    bf16* attnout = (bf16*)(ws + OFF_QKV);
    bf16* xb = (bf16*)(ws + OFF_XB);

    k_detect<<<1, 256, 0, stream>>>((const u16t*)x, flag);
    k_cvt<<<2048, 256, 0, stream>>>((const float*)x, xb, flag);
    k_trans<1536, true><<<dim3(24, 8), 256, 0, stream>>>(w_qkv, wqkvT, flag);
    k_trans<512, false><<<dim3(8, 8), 256, 0, stream>>>(w_proj, wprojT, flag);
    k_bias<<<8, 256, 0, stream>>>(b_qkv, b_proj, flag, ws);
    // fused QKV GEMM + attention: 1024 m-blocks x 8 head-pair blocks, 4 waves ea.
    k_fuse3<<<8192, 256, 0, stream>>>(x, xb, wqkvT, bq, attnout, flag);
    // proj GEMM: [131072,512] @ [512,512] -> d_out
    k_gemm<512><<<1024, 512, 0, stream>>>((const void*)attnout, attnout, wprojT, bp, d_out, flag, 2);
}

// Round 9
// 856.586 us; speedup vs baseline: 1.2873x; 1.0353x over previous
//
#include <hip/hip_runtime.h>
#include <hip/hip_bf16.h>
#include <stdint.h>

typedef __bf16 bf16;
typedef __bf16 bf16x8 __attribute__((ext_vector_type(8)));
typedef float f32x4 __attribute__((ext_vector_type(4)));
typedef unsigned short u16t;
typedef unsigned int u32t;

#define MFMA16(a, b, c) __builtin_amdgcn_mfma_f32_16x16x32_bf16((a), (b), (c), 0, 0, 0)

typedef const void __attribute__((address_space(1))) cg_void;
typedef void __attribute__((address_space(3))) lds_void;
#define GLL16(g, l) __builtin_amdgcn_global_load_lds((cg_void*)(g), (lds_void*)(l), 16, 0, 0)
#define VWAIT(n) asm volatile("s_waitcnt vmcnt(" #n ")" ::: "memory")

// ---------------- ws layout (bytes) ----------------
#define OFF_FLAG   0
#define OFF_BQKV   256
#define OFF_BPROJ  6400
#define OFF_WQKVT  8448
#define OFF_WPROJT 1581312
#define OFF_QKV    2105600      // attn-out (134 MB; qkv never materialized)
#define OFF_XB     404758784    // xb (bf16 x, 134 MB)

// head-triple permutation: reordered-W^T row n <- original qkv col src(n)
// h = n/96, r = n%96, part = r/32 (0=Q,1=K,2=V), d = r%32; src = part*512 + h*32 + d

// ---------------- dtype detector ----------------
__global__ __launch_bounds__(256) void k_detect(const u16t* x, u32t* flag) {
    __shared__ int cnt;
    if (threadIdx.x == 0) cnt = 0;
    __syncthreads();
    u16t h = x[threadIdx.x * 2];
    int e = (h >> 7) & 0xFF;
    int ok = (h == 0) || (e >= 100 && e <= 134);
    atomicAdd(&cnt, ok);
    __syncthreads();
    if (threadIdx.x == 0) flag[0] = (cnt >= 200) ? 1u : 0u;
}

// ---------------- x f32 -> bf16 pre-pass (skipped when input already bf16) ----
__global__ __launch_bounds__(256) void k_cvt(const float* x, bf16* xb, const u32t* flagp) {
    if (flagp[0]) return;
    const size_t TOT = (size_t)131072 * 512;
    size_t i = (size_t)(blockIdx.x * 256 + threadIdx.x) * 8;
    const size_t stride = (size_t)gridDim.x * 256 * 8;
    for (; i < TOT; i += stride) {
        float4 v0 = *(const float4*)(x + i);
        float4 v1 = *(const float4*)(x + i + 4);
        bf16x8 h;
        h[0] = (bf16)v0.x; h[1] = (bf16)v0.y; h[2] = (bf16)v0.z; h[3] = (bf16)v0.w;
        h[4] = (bf16)v1.x; h[5] = (bf16)v1.y; h[6] = (bf16)v1.z; h[7] = (bf16)v1.w;
        *(bf16x8*)(xb + i) = h;
    }
}

// ---------------- weight transpose: W[512][N] -> Wt[N][512] bf16 ----------------
template <int N, bool PERM>
__global__ __launch_bounds__(256) void k_trans(const void* W, bf16* Wt, const u32t* flagp) {
    __shared__ float T[64][65];
    const int isbf = (int)flagp[0];
    const int n0 = blockIdx.x * 64, k0 = blockIdx.y * 64;
    const int t = threadIdx.x;
    const int lc = t & 63, lr = t >> 6;
#pragma unroll
    for (int rr = 0; rr < 16; ++rr) {
        int row = rr * 4 + lr;
        int col = n0 + lc;
        int srcc = col;
        if (PERM) {
            int h = col / 96, r = col % 96;
            srcc = (r >> 5) * 512 + h * 32 + (r & 31);
        }
        size_t g = (size_t)(k0 + row) * N + srcc;
        float v = isbf ? (float)((const bf16*)W)[g] : ((const float*)W)[g];
        T[row][lc] = v;
    }
    __syncthreads();
#pragma unroll
    for (int rr = 0; rr < 16; ++rr) {
        int row = rr * 4 + lr;
        Wt[(size_t)(n0 + row) * 512 + k0 + lc] = (bf16)T[lc][row];
    }
}

// ---------------- bias prep -> f32 (bq permuted to head-triple order) ----------
__global__ __launch_bounds__(256) void k_bias(const void* b_qkv, const void* b_proj,
                                              const u32t* flagp, char* ws) {
    float* bq = (float*)(ws + OFF_BQKV);
    float* bp = (float*)(ws + OFF_BPROJ);
    const int isbf = (int)flagp[0];
    int gid = blockIdx.x * 256 + threadIdx.x;
    if (gid < 1536) {
        int h = gid / 96, r = gid % 96;
        int src = (r >> 5) * 512 + h * 32 + (r & 31);
        bq[gid] = isbf ? (float)((const bf16*)b_qkv)[src] : ((const float*)b_qkv)[src];
    } else if (gid < 2048) {
        int o = gid - 1536;
        bp[o] = isbf ? (float)((const bf16*)b_proj)[o] : ((const float*)b_proj)[o];
    }
}

// ---------------- proj GEMM (round-3 256^2 8-phase template, unchanged) -------
template <int NTOT>
__global__ __launch_bounds__(512, 2) void k_gemm(const void* Ax, const bf16* Axb, const bf16* Bt,
                                                 const float* bias, void* Cp,
                                                 const u32t* flagp, int omode) {
    __shared__ __align__(16) u16t As[2 * 16384];
    __shared__ __align__(16) u16t Bs[2 * 16384];
    constexpr int NBN = NTOT / 256;
    const int isbf = (int)flagp[0];
    const int out_bf16 = (omode == 1) || isbf;
    const bf16* Ab = isbf ? (const bf16*)Ax : Axb;

    const int t = threadIdx.x;
    const int w = t >> 6, lane = t & 63;
    const int ln = lane & 15, qd = lane >> 4;
    const int wm = w >> 2, wn = w & 3;

    const int flat = blockIdx.x;
    const int xcd = flat & 7, slot = flat >> 3;
    const int n_idx = slot % NBN, grp = slot / NBN;
    const int m0 = (grp * 8 + xcd) * 256;
    const int n0 = n_idx * 256;

    const int l8 = lane >> 3, pc = lane & 7;
    const int cs8 = (pc ^ l8) * 8;
    u32t aoff[2][2], boff[2][2];
    int adst[2][2], bdst[2][2];
#pragma unroll
    for (int s = 0; s < 2; ++s)
#pragma unroll
        for (int q2 = 0; q2 < 2; ++q2) {
            int rA = q2 * 128 + s * 64 + w * 8;
            aoff[s][q2] = (u32t)(m0 + rA + l8) * 512 + cs8;
            adst[s][q2] = rA * 64;
            int rB = (q2 * 2 + (w >> 2)) * 64 + s * 32 + (w & 3) * 8;
            boff[s][q2] = (u32t)(n0 + rB + l8) * 512 + cs8;
            bdst[s][q2] = rB * 64;
        }

    const int p0 = (qd ^ (ln & 7)) * 8;
    int abase[4], bbase[2];
#pragma unroll
    for (int i = 0; i < 4; ++i) abase[i] = (wm * 128 + i * 16 + ln) * 64 + p0;
#pragma unroll
    for (int j = 0; j < 2; ++j) bbase[j] = (wn * 64 + j * 16 + ln) * 64 + p0;

    f32x4 acc[8][4];
    f32x4 zero = {0.f, 0.f, 0.f, 0.f};
#pragma unroll
    for (int i = 0; i < 8; ++i)
#pragma unroll
        for (int j = 0; j < 4; ++j) acc[i][j] = zero;

    auto stageA = [&](int s, int buf, int kt) {
#pragma unroll
        for (int q2 = 0; q2 < 2; ++q2)
            GLL16(Ab + aoff[s][q2] + kt * 64, &As[buf * 16384 + adst[s][q2]]);
    };
    auto stageB = [&](int s, int buf, int kt) {
#pragma unroll
        for (int q2 = 0; q2 < 2; ++q2)
            GLL16(Bt + boff[s][q2] + kt * 64, &Bs[buf * 16384 + bdst[s][q2]]);
    };

#define PH(BUF, QM, QN, STG, WAITOP)                                             \
    {                                                                            \
        bf16x8 af[4][2], bv[2][2];                                               \
        const u16t* Ap = &As[(BUF) * 16384 + (QM) * 4096];                       \
        const u16t* Bp = &Bs[(BUF) * 16384 + (QN) * 2048];                       \
        _Pragma("unroll") for (int i = 0; i < 4; ++i) {                          \
            af[i][0] = *(const bf16x8*)(const void*)&Ap[abase[i]];               \
            af[i][1] = *(const bf16x8*)(const void*)&Ap[abase[i] ^ 32];          \
        }                                                                        \
        _Pragma("unroll") for (int j = 0; j < 2; ++j) {                          \
            bv[j][0] = *(const bf16x8*)(const void*)&Bp[bbase[j]];               \
            bv[j][1] = *(const bf16x8*)(const void*)&Bp[bbase[j] ^ 32];          \
        }                                                                        \
        STG;                                                                     \
        WAITOP;                                                                  \
        __builtin_amdgcn_s_barrier();                                            \
        __builtin_amdgcn_s_setprio(1);                                           \
        _Pragma("unroll") for (int i = 0; i < 4; ++i)                            \
            _Pragma("unroll") for (int j = 0; j < 2; ++j) {                      \
                acc[(QM) * 4 + i][(QN) * 2 + j] =                                \
                    MFMA16(af[i][0], bv[j][0], acc[(QM) * 4 + i][(QN) * 2 + j]); \
                acc[(QM) * 4 + i][(QN) * 2 + j] =                                \
                    MFMA16(af[i][1], bv[j][1], acc[(QM) * 4 + i][(QN) * 2 + j]); \
            }                                                                    \
        __builtin_amdgcn_s_setprio(0);                                           \
        __builtin_amdgcn_s_barrier();                                            \
    }

    stageA(0, 0, 0);
    stageB(0, 0, 0);
    stageB(1, 0, 0);
    stageA(1, 0, 0);
    VWAIT(4);
    __builtin_amdgcn_s_barrier();

    for (int kt = 0; kt < 7; ++kt) {
        const int buf = kt & 1, nb = buf ^ 1, k1 = kt + 1;
        PH(buf, 0, 0, stageA(0, nb, k1), VWAIT(4));
        PH(buf, 0, 1, stageB(0, nb, k1), VWAIT(4));
        PH(buf, 1, 0, stageB(1, nb, k1), VWAIT(6));
        PH(buf, 1, 1, stageA(1, nb, k1), VWAIT(4));
    }
    PH(1, 0, 0, (void)0, VWAIT(2));
    PH(1, 0, 1, (void)0, VWAIT(0));
    PH(1, 1, 0, (void)0, (void)0);
    PH(1, 1, 1, (void)0, (void)0);
#undef PH

    float bj[4];
#pragma unroll
    for (int j = 0; j < 4; ++j) bj[j] = bias[n0 + wn * 64 + j * 16 + ln];

    if (out_bf16) {
        bf16* C = (bf16*)Cp;
#pragma unroll
        for (int i = 0; i < 8; ++i)
#pragma unroll
            for (int j = 0; j < 4; ++j)
#pragma unroll
                for (int rr = 0; rr < 4; ++rr) {
                    size_t row = (size_t)m0 + wm * 128 + i * 16 + qd * 4 + rr;
                    int col = n0 + wn * 64 + j * 16 + ln;
                    C[row * NTOT + col] = (bf16)(acc[i][j][rr] + bj[j]);
                }
    } else {
        float* C = (float*)Cp;
#pragma unroll
        for (int i = 0; i < 8; ++i)
#pragma unroll
            for (int j = 0; j < 4; ++j)
#pragma unroll
                for (int rr = 0; rr < 4; ++rr) {
                    size_t row = (size_t)m0 + wm * 128 + i * 16 + qd * 4 + rr;
                    int col = n0 + wn * 64 + j * 16 + ln;
                    C[row * NTOT + col] = acc[i][j][rr] + bj[j];
                }
    }
}

// ---------------- FUSE4: fuse3 with BK=32 -> 53 KB LDS -> 3 blocks/CU ---------
// Block: BM=128 (2 windows) x BN=192 (2 heads); 8192 blocks x 256 thr = 4 waves.
// Wave (wm,wn) owns (win, head g): acc[4][6] = full Q|K|V triple.
// LDS pool 53248 B = max(staging 40 KB, attn patches 4x13312 B). 3 blocks/CU.
// Staging: A 2x4096 u16 @0; B 2x6144 u16 @8192. BK=32 -> 16 K-tiles, 3 phases
// each (j-pairs {0,1},{2,3},{4,5}; 8 MFMA). B partitioned into regions
// R0/R1/R2 (R_r = rows [r*32..+32) of each wave-half) staged 1 inst/wave each;
// A = 2 insts/wave. Uniform 5 loads/wave/tile.
// Ledger (issue: A,R0 @P0; R1 @P1; R2 @P2 -- all for tile t+1):
//   P0: VWAIT(4) ensures R1(t) [read at P1(t)]
//   P1: VWAIT(4) ensures R2(t) [read at P2(t)]
//   P2: VWAIT(2) ensures A(t+1),R0(t+1) [read at P0(t+1)]
// Never drains mid-loop; tail t=15: VWAIT(1)/(0)/none. Stage targets buffer
// last read >=4 barriers earlier. Phase skeleton identical to validated fuse3:
// {reads, stage-issue, wait, barrier, setprio-MFMA, barrier}.
// Per-acc K-order: 16 ascending 32-wide steps == fuse3's 8x{kk0,kk1} -> absmax
// bit-identical.
// Chunk swizzle (4 chunks of 16B per row): phys = c ^ (row&3); staged via
// inverse-swizzled source; frag read offset (qd ^ (ln&3))*8 -- bank-balanced
// (8 lanes per 4-bank slot = exactly the b128 minimum).
__global__ __launch_bounds__(256, 3) void k_fuse4(const void* Ax, const bf16* Axb,
                                                  const bf16* Bt, const float* bias,
                                                  bf16* attnout, const u32t* flagp) {
    __shared__ __align__(16) u16t pool[26624];
    const int isbf = (int)flagp[0];
    const bf16* Ab = isbf ? (const bf16*)Ax : Axb;

    const int t = threadIdx.x;
    const int w = t >> 6, lane = t & 63;
    const int ln = lane & 15, qd = lane >> 4, q8 = qd * 8;
    const int wm = w >> 1, wn = w & 1;

    const int flat = blockIdx.x;
    const int xcd = flat & 7, slot = flat >> 3;
    const int n_idx = slot & 7, mgrp = slot >> 3;
    const int blkm = mgrp * 8 + xcd;             // 0..1023 (bijective)
    const int m0 = blkm * 128;
    const int n0 = n_idx * 192;
    const int win = blkm * 2 + wm;
    const int g = n_idx * 2 + wn;

    // staging source swizzle: lane covers row base+(lane>>2), phys chunk lane&3;
    // source chunk c = (lane&3) ^ (row&3) = (lane&3) ^ ((lane>>2)&3)
    const int l4 = lane >> 2;
    const int csw = ((lane & 3) ^ (l4 & 3)) * 8;

    // A staging: 2 insts/wave, rows [w*32+q*16, +16)
    u32t asrc[2];
    int adst[2];
#pragma unroll
    for (int q = 0; q < 2; ++q) {
        int r0 = w * 32 + q * 16;
        asrc[q] = (u32t)(m0 + r0 + l4) * 512 + csw;
        adst[q] = r0 * 32;
    }
    // B staging: 1 inst/wave/region; region r base = r*32 + (w&1)*16 + (w>>1)*96
    u32t bsrc[3];
    int bdst[3];
#pragma unroll
    for (int r = 0; r < 3; ++r) {
        int rb = r * 32 + (w & 1) * 16 + (w >> 1) * 96;
        bsrc[r] = (u32t)(n0 + rb + l4) * 512 + csw;
        bdst[r] = rb * 32;
    }

    // fragment read bases (u16); chunk qd, phys = qd ^ (row&3) = qd ^ (ln&3)
    const int ck = (qd ^ (ln & 3)) * 8;
    int afo[4], bfo[6];
#pragma unroll
    for (int i = 0; i < 4; ++i) afo[i] = (wm * 64 + i * 16 + ln) * 32 + ck;
#pragma unroll
    for (int j = 0; j < 6; ++j) bfo[j] = (wn * 96 + j * 16 + ln) * 32 + ck;

    f32x4 acc[4][6];
    f32x4 zero = {0.f, 0.f, 0.f, 0.f};
#pragma unroll
    for (int i = 0; i < 4; ++i)
#pragma unroll
        for (int j = 0; j < 6; ++j) acc[i][j] = zero;

    auto ST_A = [&](int buf, int kt) {
#pragma unroll
        for (int q = 0; q < 2; ++q)
            GLL16(Ab + asrc[q] + kt * 32, &pool[buf * 4096 + adst[q]]);
    };
    auto ST_R = [&](int r, int buf, int kt) {
        GLL16(Bt + bsrc[r] + kt * 32, &pool[8192 + buf * 6144 + bdst[r]]);
    };

    // prologue: tile 0 -> buf 0 (order A,A,R0,R1,R2); A0+R0 needed -> VWAIT(2)
    ST_A(0, 0);
    ST_R(0, 0, 0);
    ST_R(1, 0, 0);
    ST_R(2, 0, 0);
    VWAIT(2);
    __builtin_amdgcn_s_barrier();

    for (int kt = 0; kt < 16; ++kt) {
        const int buf = kt & 1, nb = buf ^ 1;
        const u16t* Abuf = &pool[buf * 4096];
        const u16t* Bbuf = &pool[8192 + buf * 6144];
        bf16x8 af[4], bv[2];

        // ---- P0: A-frags + j{0,1} ----
#pragma unroll
        for (int i = 0; i < 4; ++i)
            af[i] = *(const bf16x8*)(const void*)&Abuf[afo[i]];
        bv[0] = *(const bf16x8*)(const void*)&Bbuf[bfo[0]];
        bv[1] = *(const bf16x8*)(const void*)&Bbuf[bfo[1]];
        if (kt < 15) { ST_A(nb, kt + 1); ST_R(0, nb, kt + 1); VWAIT(4); }
        else VWAIT(1);
        __builtin_amdgcn_s_barrier();
        __builtin_amdgcn_s_setprio(1);
#pragma unroll
        for (int i = 0; i < 4; ++i) {
            acc[i][0] = MFMA16(af[i], bv[0], acc[i][0]);
            acc[i][1] = MFMA16(af[i], bv[1], acc[i][1]);
        }
        __builtin_amdgcn_s_setprio(0);
        __builtin_amdgcn_s_barrier();

        // ---- P1: j{2,3} ----
        bv[0] = *(const bf16x8*)(const void*)&Bbuf[bfo[2]];
        bv[1] = *(const bf16x8*)(const void*)&Bbuf[bfo[3]];
        if (kt < 15) { ST_R(1, nb, kt + 1); VWAIT(4); }
        else VWAIT(0);
        __builtin_amdgcn_s_barrier();
        __builtin_amdgcn_s_setprio(1);
#pragma unroll
        for (int i = 0; i < 4; ++i) {
            acc[i][2] = MFMA16(af[i], bv[0], acc[i][2]);
            acc[i][3] = MFMA16(af[i], bv[1], acc[i][3]);
        }
        __builtin_amdgcn_s_setprio(0);
        __builtin_amdgcn_s_barrier();

        // ---- P2: j{4,5} ----
        bv[0] = *(const bf16x8*)(const void*)&Bbuf[bfo[4]];
        bv[1] = *(const bf16x8*)(const void*)&Bbuf[bfo[5]];
        if (kt < 15) { ST_R(2, nb, kt + 1); VWAIT(2); }
        __builtin_amdgcn_s_barrier();
        __builtin_amdgcn_s_setprio(1);
#pragma unroll
        for (int i = 0; i < 4; ++i) {
            acc[i][4] = MFMA16(af[i], bv[0], acc[i][4]);
            acc[i][5] = MFMA16(af[i], bv[1], acc[i][5]);
        }
        __builtin_amdgcn_s_setprio(0);
        __builtin_amdgcn_s_barrier();
    }

    // ---- stash Q,K,V (+bias) into the wave's PRIVATE patch (no block sync) ----
    float bj[6];
#pragma unroll
    for (int j = 0; j < 6; ++j) bj[j] = bias[g * 96 + j * 16 + ln];
    u16t* pw = &pool[w * 6656];
#pragma unroll
    for (int i = 0; i < 4; ++i)
#pragma unroll
        for (int j = 0; j < 6; ++j) {
            int part = j >> 1;                     // 0=Q 1=K 2=V
            int d = (j & 1) * 16 + ln;
#pragma unroll
            for (int rr = 0; rr < 4; ++rr) {
                int tok = i * 16 + qd * 4 + rr;
                bf16 val = (bf16)(acc[i][j][rr] + bj[j]);
                int idx;
                if (part == 2)
                    idx = 4608 + tok * 32 +
                          (((d >> 3) ^ (((tok >> 3) ^ tok) & 3)) << 3) + (d & 7);
                else
                    idx = part * 2048 + tok * 32 +
                          (((d >> 3) ^ ((tok >> 1) & 3)) << 3) + (d & 7);
                *(bf16*)&pw[idx] = val;
            }
        }

    // ---- attention for (win, head g): verbatim validated math ----
    {
        const int hcol = g * 32;
        const int qswz = (qd ^ ((ln >> 1) & 3)) * 8;

        bf16x8 aq[4], bk[4];
#pragma unroll
        for (int i = 0; i < 4; ++i)
            aq[i] = *(const bf16x8*)(const void*)&pw[(i * 16 + ln) * 32 + qswz];
#pragma unroll
        for (int j = 0; j < 4; ++j)
            bk[j] = *(const bf16x8*)(const void*)&pw[2048 + (j * 16 + ln) * 32 + qswz];

        f32x4 zro = {0.f, 0.f, 0.f, 0.f};
        f32x4 s[4][4];
#pragma unroll
        for (int i = 0; i < 4; ++i)
#pragma unroll
            for (int j = 0; j < 4; ++j) s[i][j] = MFMA16(aq[i], bk[j], zro);

        const float INV2S2 = 3.28731097961867f;  // 1/(2*0.39^2)
        {
            int c = lane & 7;
            float S1 = 0.f;
#pragma unroll
            for (int c2 = 0; c2 < 8; ++c2) {
                int dd = c - c2;
                S1 += __expf(-(float)(dd * dd) * INV2S2);
            }
            float invS1 = 1.0f / S1;
            const int ymb = ln >> 3, xm = ln & 7, yq = qd >> 1, xq = (qd & 1) * 4;
            float FY[4][4], FX[4];
#pragma unroll
            for (int i = 0; i < 4; ++i) {
                int yn = 2 * i + yq;
                float gg = __shfl(invS1, yn, 64);
#pragma unroll
                for (int j = 0; j < 4; ++j) {
                    int dy = yn - (2 * j + ymb);
                    FY[i][j] = __expf(-(float)(dy * dy) * INV2S2) * gg;
                }
            }
#pragma unroll
            for (int rr = 0; rr < 4; ++rr) {
                int xn = xq + rr;
                int dx = xn - xm;
                FX[rr] = __expf(-(float)(dx * dx) * INV2S2) * __shfl(invS1, xn, 64);
            }

            const float SCALE = 0.17677669529663687f;  // 1/sqrt(32)
#pragma unroll
            for (int i = 0; i < 4; ++i)
#pragma unroll
                for (int rr = 0; rr < 4; ++rr) {
                    float lj[4];
                    float mx = -1e30f;
#pragma unroll
                    for (int j = 0; j < 4; ++j) {
                        lj[j] = s[i][j][rr] * SCALE * FY[i][j] * FX[rr];
                        mx = fmaxf(mx, lj[j]);
                    }
                    mx = fmaxf(mx, __shfl_xor(mx, 1));
                    mx = fmaxf(mx, __shfl_xor(mx, 2));
                    mx = fmaxf(mx, __shfl_xor(mx, 4));
                    mx = fmaxf(mx, __shfl_xor(mx, 8));
                    float sum = 0.f;
#pragma unroll
                    for (int j = 0; j < 4; ++j) {
                        lj[j] = __expf(lj[j] - mx);
                        sum += lj[j];
                    }
                    sum += __shfl_xor(sum, 1);
                    sum += __shfl_xor(sum, 2);
                    sum += __shfl_xor(sum, 4);
                    sum += __shfl_xor(sum, 8);
                    float inv = 1.0f / sum;
                    int n = i * 16 + qd * 4 + rr;
#pragma unroll
                    for (int j = 0; j < 4; ++j) {
                        bf16 pv = (bf16)(lj[j] * inv);
                        *(bf16*)&pw[n * 72 + j * 16 + ln] = pv;
                    }
                }
        }

        f32x4 o[4][2];
#pragma unroll
        for (int i = 0; i < 4; ++i) {
            o[i][0] = zro;
            o[i][1] = zro;
        }
#pragma unroll
        for (int kc = 0; kc < 64; kc += 32) {
            bf16x8 bv2[2];
#pragma unroll
            for (int j2 = 0; j2 < 2; ++j2) {
                int cc = j2 * 2 + (ln >> 3);
#pragma unroll
                for (int jj = 0; jj < 8; ++jj) {
                    int rv = kc + q8 + jj;
                    bv2[j2][jj] = *(const bf16*)&pw[4608 + rv * 32 +
                                                   ((cc ^ (((rv >> 3) ^ rv) & 3)) << 3) + (ln & 7)];
                }
            }
#pragma unroll
            for (int i = 0; i < 4; ++i) {
                bf16x8 ap = *(const bf16x8*)(const void*)&pw[(i * 16 + ln) * 72 + kc + q8];
#pragma unroll
                for (int j2 = 0; j2 < 2; ++j2) o[i][j2] = MFMA16(ap, bv2[j2], o[i][j2]);
            }
        }
#pragma unroll
        for (int i = 0; i < 4; ++i)
#pragma unroll
            for (int j2 = 0; j2 < 2; ++j2)
#pragma unroll
                for (int rr = 0; rr < 4; ++rr)
                    attnout[((size_t)win * 64 + i * 16 + qd * 4 + rr) * 512 +
                            hcol + j2 * 16 + ln] = (bf16)(o[i][j2][rr]);
    }
}

extern "C" void kernel_launch(void* const* d_in, const int* in_sizes, int n_in,
                              void* d_out, int out_size, void* d_ws, size_t ws_size,
                              hipStream_t stream) {
    const void* x = d_in[0];
    const void* w_qkv = d_in[1];
    const void* b_qkv = d_in[2];
    const void* w_proj = d_in[3];
    const void* b_proj = d_in[4];
    char* ws = (char*)d_ws;
    u32t* flag = (u32t*)(ws + OFF_FLAG);
    bf16* wqkvT = (bf16*)(ws + OFF_WQKVT);
    bf16* wprojT = (bf16*)(ws + OFF_WPROJT);
    float* bq = (float*)(ws + OFF_BQKV);
    float* bp = (float*)(ws + OFF_BPROJ);
    bf16* attnout = (bf16*)(ws + OFF_QKV);
    bf16* xb = (bf16*)(ws + OFF_XB);

    k_detect<<<1, 256, 0, stream>>>((const u16t*)x, flag);
    k_cvt<<<2048, 256, 0, stream>>>((const float*)x, xb, flag);
    k_trans<1536, true><<<dim3(24, 8), 256, 0, stream>>>(w_qkv, wqkvT, flag);
    k_trans<512, false><<<dim3(8, 8), 256, 0, stream>>>(w_proj, wprojT, flag);
    k_bias<<<8, 256, 0, stream>>>(b_qkv, b_proj, flag, ws);
    // fused QKV GEMM + attention: 1024 m-blocks x 8 head-pair blocks, 4 waves ea.
    k_fuse4<<<8192, 256, 0, stream>>>(x, xb, wqkvT, bq, attnout, flag);
    // proj GEMM: [131072,512] @ [512,512] -> d_out
    k_gemm<512><<<1024, 512, 0, stream>>>((const void*)attnout, attnout, wprojT, bp, d_out, flag, 2);
}